// Round 6
// baseline (223.408 us; speedup 1.0000x reference)
//
#include <hip/hip_runtime.h>
#include <hip/hip_cooperative_groups.h>
#include <math.h>
#include <stdint.h>

namespace cg = cooperative_groups;

#define B_    8
#define N_    2048
#define FIN   256
#define FO    128
#define ALPHA 0.2f
#define NCHUNK 64
#define CHUNK  32   // N_/NCHUNK
#define NBLK  256
#define NTHR  512

// ---------------- workspace layout (float elements) ----------------
static const size_t OFF_WH    = 0;                                   // B*N*FO
static const size_t OFF_S1    = OFF_WH    + (size_t)B_*N_*FO;
static const size_t OFF_S2    = OFF_S1    + (size_t)B_*N_;
static const size_t OFF_SSORT = OFF_S2    + (size_t)B_*N_;
static const size_t OFF_SORD  = OFF_SSORT + (size_t)B_*N_;
static const size_t OFF_E2P   = OFF_SORD  + (size_t)B_*N_;
static const size_t OFF_E2N   = OFF_E2P   + (size_t)B_*N_;
static const size_t OFF_DPN   = OFF_E2N   + (size_t)B_*N_;           // float2 * B*N
static const size_t OFF_KCUT  = OFF_DPN   + (size_t)2*B_*N_;
static const size_t OFF_OFFS  = OFF_KCUT  + (size_t)B_*N_;           // float2 * B*NCHUNK*FO
static const size_t OFF_SNTOT = OFF_OFFS  + (size_t)2*B_*NCHUNK*FO;
static const size_t OFF_CT    = OFF_SNTOT + (size_t)B_*FO;           // float2 * B*NCHUNK*FO
static const size_t OFF_SUB   = OFF_CT    + (size_t)2*B_*NCHUNK*FO;  // float2 * B*NCHUNK*3*FO

// ---------------- fully fused cooperative kernel ----------------
// 256 blocks x 512 threads, 1 block/CU. LDS overlay:
//   phase1 GEMM : hS[32][68] (8704) | wS[32][128] (16384) | red 2*64*36 (18432) = 43520
//   phase2 rank : keys[2048] u64 (16384) | part[512] (2048)
//   phase3 kx   : qt[4][128] f2 (4096) | sv[2048] (8192) | wsum[8] f2 (64)
//   phase4 offs : ct[64][128] f2 (65536) | qTot[4][128] f2 (4096) = 69632
__global__ __launch_bounds__(NTHR) void fused(const float* __restrict__ h,
                                              const float* __restrict__ W,
                                              const float* __restrict__ a,
                                              float* __restrict__ out,
                                              float* __restrict__ Wh,
                                              float* __restrict__ s1g,
                                              float* __restrict__ s2g,
                                              float* __restrict__ ssort,
                                              int* __restrict__ sord,
                                              float* __restrict__ e2p,
                                              float* __restrict__ e2n,
                                              float2* __restrict__ DPN,
                                              int* __restrict__ kcut,
                                              float2* __restrict__ OFFS,
                                              float* __restrict__ SNtot,
                                              float2* __restrict__ CT,
                                              float2* __restrict__ SUB) {
    __shared__ __align__(16) unsigned char smem[69632];
    cg::grid_group grid = cg::this_grid();
    const int tid = threadIdx.x;
    const int bid = blockIdx.x;

    // ================= Phase 1: GEMM Wh = h@W, fused s1/s2 =================
    {
        float (*hS)[68]  = (float(*)[68])smem;                 // [k][m] transposed
        float (*wS)[128] = (float(*)[128])(smem + 8704);       // [k][n]
        float (*red)[64][36] = (float(*)[64][36])(smem + 25088);

        const int tn = tid & 31;     // cols 4*tn..+3
        const int tm = tid >> 5;     // rows 4*tm..+3  (0..15)
        const int row0 = bid * 64;
        const int h_r = tid >> 3, h_c0 = (tid & 7) * 4;

        float acc[4][4];
#pragma unroll
        for (int m = 0; m < 4; ++m)
#pragma unroll
            for (int c = 0; c < 4; ++c) acc[m][c] = 0.f;

        float4 ha, wreg[2];
        ha = *(const float4*)&h[(size_t)(row0 + h_r) * FIN + h_c0];
#pragma unroll
        for (int p = 0; p < 2; ++p) {
            int idx = p * NTHR + tid, kW = idx >> 5, n4 = (idx & 31) * 4;
            wreg[p] = *(const float4*)&W[(size_t)kW * FO + n4];
        }

        for (int kt = 0; kt < FIN; kt += 32) {
            hS[h_c0 + 0][h_r] = ha.x; hS[h_c0 + 1][h_r] = ha.y;
            hS[h_c0 + 2][h_r] = ha.z; hS[h_c0 + 3][h_r] = ha.w;
#pragma unroll
            for (int p = 0; p < 2; ++p) {
                int idx = p * NTHR + tid, kW = idx >> 5, n4 = (idx & 31) * 4;
                *(float4*)&wS[kW][n4] = wreg[p];
            }
            __syncthreads();

            if (kt + 32 < FIN) {
                ha = *(const float4*)&h[(size_t)(row0 + h_r) * FIN + kt + 32 + h_c0];
#pragma unroll
                for (int p = 0; p < 2; ++p) {
                    int idx = p * NTHR + tid, kW = idx >> 5, n4 = (idx & 31) * 4;
                    wreg[p] = *(const float4*)&W[(size_t)(kt + 32 + kW) * FO + n4];
                }
            }

#pragma unroll 8
            for (int kk = 0; kk < 32; ++kk) {
                float4 hv = *(float4*)&hS[kk][4 * tm];
                float4 wv = *(float4*)&wS[kk][4 * tn];
                float hm[4] = {hv.x, hv.y, hv.z, hv.w};
                float wn4[4] = {wv.x, wv.y, wv.z, wv.w};
#pragma unroll
                for (int m = 0; m < 4; ++m)
#pragma unroll
                    for (int c = 0; c < 4; ++c)
                        acc[m][c] += hm[m] * wn4[c];
            }
            __syncthreads();
        }

#pragma unroll
        for (int m = 0; m < 4; ++m) {
            float4 o = make_float4(acc[m][0], acc[m][1], acc[m][2], acc[m][3]);
            *(float4*)&Wh[(size_t)(row0 + 4 * tm + m) * FO + 4 * tn] = o;
        }

        float a1v[4], a2v[4];
#pragma unroll
        for (int c = 0; c < 4; ++c) {
            a1v[c] = a[4 * tn + c];
            a2v[c] = a[FO + 4 * tn + c];
        }
#pragma unroll
        for (int m = 0; m < 4; ++m) {
            float p1 = 0.f, p2 = 0.f;
#pragma unroll
            for (int c = 0; c < 4; ++c) {
                p1 += acc[m][c] * a1v[c];
                p2 += acc[m][c] * a2v[c];
            }
            red[0][4 * tm + m][tn] = p1;
            red[1][4 * tm + m][tn] = p2;
        }
        __syncthreads();
        if (tid < 128) {
            int arr = tid >> 6, li = tid & 63;
            float s = 0.f;
#pragma unroll
            for (int g = 0; g < 32; ++g) s += red[arr][li][g];
            (arr ? s2g : s1g)[row0 + li] = s;
        }
    }
    grid.sync();

    // ================= Phase 2: rank + scatter + exps =================
    {
        uint64_t* keys = (uint64_t*)smem;
        int* part = (int*)(smem + 16384);
        const int b = bid >> 5, c = bid & 31;

        for (int t = tid; t < N_; t += NTHR) {
            unsigned u = __float_as_uint(s2g[b * N_ + t]);
            u = (u & 0x80000000u) ? ~u : (u | 0x80000000u);
            keys[t] = ((uint64_t)u << 16) | (unsigned)t;
        }
        __syncthreads();

        const int le = tid & 63;
        const int e  = c * 64 + le;
        const int q  = tid >> 6;
        const uint64_t myk = keys[e];
        const uint64_t* kp = keys + q * 256;
        int cnt = 0;
#pragma unroll 8
        for (int kk = 0; kk < 256; ++kk) cnt += (int)(kp[kk] > myk);
        part[tid] = cnt;
        __syncthreads();

        if (tid < 64) {
            int rank = 0;
#pragma unroll
            for (int g = 0; g < 8; ++g) rank += part[tid + 64 * g];
            int ee = c * 64 + tid;
            float v = s2g[b * N_ + ee];
            ssort[b * N_ + rank] = v;
            sord[b * N_ + rank]  = ee;
            e2p[b * N_ + rank] = expf(v);
            e2n[b * N_ + rank] = expf(ALPHA * v);
        }
    }
    grid.sync();

    // ================= Phase 3: chunk sums (2 jobs/block) + scalar scan/cutoffs =================
    {
        float2 (*qt)[128] = (float2(*)[128])smem;
        float* sv = (float*)(smem + 4096);
        float2* wsum = (float2*)(smem + 4096 + 8192);

        // --- two chunk jobs ---
        const int f = tid & 127, q = tid >> 7;
#pragma unroll
        for (int jj = 0; jj < 2; ++jj) {
            const int job = bid + jj * NBLK;
            const int b = job >> 6, ch = job & 63;
            const size_t base = (size_t)b * N_;
            const int ks = ch * CHUNK + q * 8;

            int ords[8]; float wp[8], wn[8], xv[8];
#pragma unroll
            for (int j = 0; j < 8; ++j) ords[j] = sord[base + ks + j];
#pragma unroll
            for (int j = 0; j < 8; ++j) { wp[j] = e2p[base + ks + j]; wn[j] = e2n[base + ks + j]; }
#pragma unroll
            for (int j = 0; j < 8; ++j) xv[j] = Wh[(base + ords[j]) * FO + f];

            float ap = 0.f, an = 0.f;
#pragma unroll
            for (int j = 0; j < 8; ++j) { ap += wp[j] * xv[j]; an += wn[j] * xv[j]; }
            if (jj) __syncthreads();           // protect qt reuse
            qt[q][f] = make_float2(ap, an);
            __syncthreads();

            float2 t0 = qt[0][f], t1 = qt[1][f], t2 = qt[2][f];
            float op = 0.f, on = 0.f;
            if (q > 0) { op += t0.x; on += t0.y; }
            if (q > 1) { op += t1.x; on += t1.y; }
            if (q > 2) { op += t2.x; on += t2.y; }
            float2 incl = make_float2(ap + op, an + on);
            if (q < 3)
                SUB[(((size_t)b * NCHUNK + ch) * 3 + q) * FO + f] = incl;
            else
                CT[((size_t)b * NCHUNK + ch) * FO + f] = incl;
        }

        // --- blocks 0..7: per-batch scalar scans + cutoffs ---
        if (bid < B_) {
            const int b = bid;
            const size_t base = (size_t)b * N_;

            float v[4], pv[4], nv[4], lp[4], ln[4];
            *(float4*)&v[0]  = *(const float4*)&ssort[base + tid * 4];
            *(float4*)&pv[0] = *(const float4*)&e2p[base + tid * 4];
            *(float4*)&nv[0] = *(const float4*)&e2n[base + tid * 4];
            float ap = 0.f, an = 0.f;
#pragma unroll
            for (int j = 0; j < 4; ++j) {
                sv[tid * 4 + j] = v[j];
                ap += pv[j]; lp[j] = ap;
                an += nv[j]; ln[j] = an;
            }

            float ip = ap, in2 = an;
            const int lane = tid & 63;
#pragma unroll
            for (int off = 1; off < 64; off <<= 1) {
                float tpv = __shfl_up(ip, off);
                float tnv = __shfl_up(in2, off);
                if (lane >= off) { ip += tpv; in2 += tnv; }
            }
            if (lane == 63) wsum[tid >> 6] = make_float2(ip, in2);
            __syncthreads();

            float basP = ip - ap, basN = in2 - an;
            const int w = tid >> 6;
#pragma unroll
            for (int w2 = 0; w2 < 7; ++w2)
                if (w2 < w) { basP += wsum[w2].x; basN += wsum[w2].y; }
#pragma unroll
            for (int j = 0; j < 4; ++j)
                DPN[base + tid * 4 + j] = make_float2(lp[j] + basP, ln[j] + basN);

            float tgt[4];
            int lo[4], hi[4];
#pragma unroll
            for (int r = 0; r < 4; ++r) {
                tgt[r] = -s1g[base + tid + 512 * r];
                lo[r] = 0; hi[r] = N_;
            }
#pragma unroll
            for (int step = 0; step < 11; ++step) {
#pragma unroll
                for (int r = 0; r < 4; ++r) {
                    int mid = (lo[r] + hi[r]) >> 1;
                    bool live = lo[r] < hi[r];
                    float pv2 = sv[mid & (N_ - 1)];
                    bool cc = live && (pv2 >= tgt[r]);
                    lo[r] = cc ? mid + 1 : lo[r];
                    hi[r] = (live && !cc) ? mid : hi[r];
                }
            }
#pragma unroll
            for (int r = 0; r < 4; ++r) kcut[base + tid + 512 * r] = lo[r];
        }
    }
    grid.sync();

    // ================= Phase 4: chunk-offset scan (blocks 0..7) =================
    if (bid < B_) {
        float2 (*ct)[128] = (float2(*)[128])smem;              // 64 KB
        float2 (*qTot)[128] = (float2(*)[128])(smem + 65536);  // 4 KB
        const int b = bid;

        for (int idx = tid; idx < NCHUNK * FO; idx += NTHR) {
            int c = idx >> 7, f = idx & 127;
            ct[c][f] = CT[((size_t)b * NCHUNK + c) * FO + f];
        }
        __syncthreads();

        const int f = tid & 127, qq = tid >> 7;   // 4 quarter-groups x 16 chunks
        float rp = 0.f, rn = 0.f;
        for (int c = qq * 16; c < qq * 16 + 16; ++c) {
            float2 t = ct[c][f];
            ct[c][f] = make_float2(rp, rn);
            rp += t.x; rn += t.y;
        }
        qTot[qq][f] = make_float2(rp, rn);
        __syncthreads();

        float addP = 0.f, addN = 0.f;
#pragma unroll
        for (int q2 = 0; q2 < 3; ++q2)
            if (q2 < qq) { addP += qTot[q2][f].x; addN += qTot[q2][f].y; }
        for (int c = qq * 16; c < qq * 16 + 16; ++c) {
            float2 t = ct[c][f];
            OFFS[((size_t)b * NCHUNK + c) * FO + f] = make_float2(t.x + addP, t.y + addN);
        }
        if (tid < FO)
            SNtot[b * FO + tid] = qTot[0][tid].y + qTot[1][tid].y + qTot[2][tid].y + qTot[3][tid].y;
    }
    grid.sync();

    // ================= Phase 5: combine + gather tail + elu =================
    {
        const int f = tid & 127;
        const int rsub = tid >> 7;           // 0..3
#pragma unroll 2
        for (int it = 0; it < 16; ++it) {
            const int rowg = bid * 64 + it * 4 + rsub;
            const int b = rowg >> 11;
            const size_t base = (size_t)b * N_;

            const float s1v = s1g[rowg];
            const int k = kcut[rowg];

            const float ep1 = expf(s1v), en1 = expf(ALPHA * s1v);
            float dp = 0.f, dn = 0.f, sp = 0.f, sn = 0.f;
            if (k > 0) {
                const int km1 = k - 1;
                float2 d = DPN[base + km1];
                dp = d.x; dn = d.y;
                const int c32 = km1 >> 5;
                const int g = (km1 >> 3) & 3;
                float2 o = OFFS[((size_t)b * NCHUNK + c32) * FO + f];
                sp = o.x; sn = o.y;
                if (g > 0) {
                    float2 su = SUB[(((size_t)b * NCHUNK + c32) * 3 + (g - 1)) * FO + f];
                    sp += su.x; sn += su.y;
                }
                const int j0 = c32 * 32 + g * 8;
                for (int j = j0; j <= km1; ++j) {     // <=8 iters, wave-uniform
                    int ord = sord[base + j];
                    float wp = e2p[base + j];
                    float wn = e2n[base + j];
                    float x = Wh[(base + ord) * FO + f];
                    sp += wp * x;
                    sn += wn * x;
                }
            }
            const float dnt = DPN[base + N_ - 1].y;
            const float snt = SNtot[b * FO + f];

            const float den = ep1 * dp + en1 * (dnt - dn);
            const float num = ep1 * sp + en1 * (snt - sn);
            const float o = num / den;
            out[(size_t)rowg * FO + f] = (o > 0.f) ? o : (expf(o) - 1.f);
        }
    }
}

// ---------------- launch ----------------
extern "C" void kernel_launch(void* const* d_in, const int* in_sizes, int n_in,
                              void* d_out, int out_size, void* d_ws, size_t ws_size,
                              hipStream_t stream) {
    const float* h = (const float*)d_in[0];
    const float* W = (const float*)d_in[1];
    const float* a = (const float*)d_in[2];
    float* out = (float*)d_out;
    float* ws = (float*)d_ws;

    float*  Wh    = ws + OFF_WH;
    float*  s1    = ws + OFF_S1;
    float*  s2    = ws + OFF_S2;
    float*  ssort = ws + OFF_SSORT;
    int*    sord  = (int*)(ws + OFF_SORD);
    float*  e2p   = ws + OFF_E2P;
    float*  e2n   = ws + OFF_E2N;
    float2* DPN   = (float2*)(ws + OFF_DPN);
    int*    kcut  = (int*)(ws + OFF_KCUT);
    float2* OFFS  = (float2*)(ws + OFF_OFFS);
    float*  SNtot = ws + OFF_SNTOT;
    float2* CT    = (float2*)(ws + OFF_CT);
    float2* SUB   = (float2*)(ws + OFF_SUB);

    void* args[] = {(void*)&h, (void*)&W, (void*)&a, (void*)&out,
                    (void*)&Wh, (void*)&s1, (void*)&s2, (void*)&ssort,
                    (void*)&sord, (void*)&e2p, (void*)&e2n, (void*)&DPN,
                    (void*)&kcut, (void*)&OFFS, (void*)&SNtot, (void*)&CT,
                    (void*)&SUB};
    hipLaunchCooperativeKernel((void*)fused, dim3(NBLK), dim3(NTHR), args, 0, stream);
}

// Round 7
// 102.163 us; speedup vs baseline: 2.1868x; 2.1868x over previous
//
#include <hip/hip_runtime.h>
#include <math.h>
#include <stdint.h>

#define B_    8
#define N_    2048
#define FIN   256
#define FO    128
#define ALPHA 0.2f
#define NCHUNK 32
#define CHUNK  64    // N_/NCHUNK
#define NGRAIN 8     // grains per chunk, grain size 8

// ---------------- workspace layout (float elements) ----------------
static const size_t OFF_WH    = 0;                                    // B*N*FO
static const size_t OFF_S1P   = OFF_WH    + (size_t)B_*N_*FO;         // 2*B*N (two n-half partials)
static const size_t OFF_S2P   = OFF_S1P   + (size_t)2*B_*N_;          // 2*B*N
static const size_t OFF_SSORT = OFF_S2P   + (size_t)2*B_*N_;
static const size_t OFF_SORD  = OFF_SSORT + (size_t)B_*N_;
static const size_t OFF_E2P   = OFF_SORD  + (size_t)B_*N_;
static const size_t OFF_E2N   = OFF_E2P   + (size_t)B_*N_;
static const size_t OFF_DPN   = OFF_E2N   + (size_t)B_*N_;            // float2 * B*N
static const size_t OFF_KCUT  = OFF_DPN   + (size_t)2*B_*N_;
static const size_t OFF_SUB   = OFF_KCUT  + (size_t)B_*N_;            // float2 * B*NCHUNK*NGRAIN*FO

// ---------------- K1: Wh = h @ W (+ per-half partial s1,s2) ----------------
// 512 blocks: (mblk 0..255) x (nh 0..1). BM=64, BN=64. 256 threads, 4m x 4n.
// 2 blocks/CU -> 2 waves/SIMD.
__global__ __launch_bounds__(256) void k1_gemm(const float* __restrict__ h,
                                               const float* __restrict__ W,
                                               const float* __restrict__ a,
                                               float* __restrict__ Wh,
                                               float* __restrict__ s1p,
                                               float* __restrict__ s2p) {
    __shared__ __align__(16) float hS[32][68];   // [k][m] transposed, pad 68
    __shared__ __align__(16) float wS[32][64];   // [k][n-half]
    __shared__ float red[2][64][20];

    const int tid  = threadIdx.x;
    const int mblk = blockIdx.x >> 1, nh = blockIdx.x & 1;
    const int row0 = mblk * 64, col0 = nh * 64;
    const int tn = tid & 15;     // cols col0 + 4*tn .. +3
    const int tm = tid >> 4;     // rows 4*tm .. +3 (0..15)
    const int h_r = tid >> 2, h_c0 = (tid & 3) * 8;

    float acc[4][4];
#pragma unroll
    for (int m = 0; m < 4; ++m)
#pragma unroll
        for (int c = 0; c < 4; ++c) acc[m][c] = 0.f;

    float4 ha, hb, wreg[2];
    ha = *(const float4*)&h[(size_t)(row0 + h_r) * FIN + h_c0];
    hb = *(const float4*)&h[(size_t)(row0 + h_r) * FIN + h_c0 + 4];
#pragma unroll
    for (int p = 0; p < 2; ++p) {
        int idx = p * 256 + tid, kW = idx >> 4, n4 = (idx & 15) * 4;
        wreg[p] = *(const float4*)&W[(size_t)kW * FO + col0 + n4];
    }

    for (int kt = 0; kt < FIN; kt += 32) {
        hS[h_c0 + 0][h_r] = ha.x; hS[h_c0 + 1][h_r] = ha.y;
        hS[h_c0 + 2][h_r] = ha.z; hS[h_c0 + 3][h_r] = ha.w;
        hS[h_c0 + 4][h_r] = hb.x; hS[h_c0 + 5][h_r] = hb.y;
        hS[h_c0 + 6][h_r] = hb.z; hS[h_c0 + 7][h_r] = hb.w;
#pragma unroll
        for (int p = 0; p < 2; ++p) {
            int idx = p * 256 + tid, kW = idx >> 4, n4 = (idx & 15) * 4;
            *(float4*)&wS[kW][n4] = wreg[p];
        }
        __syncthreads();

        if (kt + 32 < FIN) {
            ha = *(const float4*)&h[(size_t)(row0 + h_r) * FIN + kt + 32 + h_c0];
            hb = *(const float4*)&h[(size_t)(row0 + h_r) * FIN + kt + 32 + h_c0 + 4];
#pragma unroll
            for (int p = 0; p < 2; ++p) {
                int idx = p * 256 + tid, kW = idx >> 4, n4 = (idx & 15) * 4;
                wreg[p] = *(const float4*)&W[(size_t)(kt + 32 + kW) * FO + col0 + n4];
            }
        }

#pragma unroll 8
        for (int kk = 0; kk < 32; ++kk) {
            float4 hv = *(float4*)&hS[kk][4 * tm];
            float4 wv = *(float4*)&wS[kk][4 * tn];
            float hm[4] = {hv.x, hv.y, hv.z, hv.w};
            float wn4[4] = {wv.x, wv.y, wv.z, wv.w};
#pragma unroll
            for (int m = 0; m < 4; ++m)
#pragma unroll
                for (int c = 0; c < 4; ++c)
                    acc[m][c] += hm[m] * wn4[c];
        }
        __syncthreads();
    }

#pragma unroll
    for (int m = 0; m < 4; ++m) {
        float4 o = make_float4(acc[m][0], acc[m][1], acc[m][2], acc[m][3]);
        *(float4*)&Wh[(size_t)(row0 + 4 * tm + m) * FO + col0 + 4 * tn] = o;
    }

    // per-half partial s1/s2
    float a1v[4], a2v[4];
#pragma unroll
    for (int c = 0; c < 4; ++c) {
        a1v[c] = a[col0 + 4 * tn + c];
        a2v[c] = a[FO + col0 + 4 * tn + c];
    }
#pragma unroll
    for (int m = 0; m < 4; ++m) {
        float p1 = 0.f, p2 = 0.f;
#pragma unroll
        for (int c = 0; c < 4; ++c) {
            p1 += acc[m][c] * a1v[c];
            p2 += acc[m][c] * a2v[c];
        }
        red[0][4 * tm + m][tn] = p1;
        red[1][4 * tm + m][tn] = p2;
    }
    __syncthreads();
    if (tid < 128) {
        int arr = tid >> 6, li = tid & 63;
        float s = 0.f;
#pragma unroll
        for (int g = 0; g < 16; ++g) s += red[arr][li][g];
        (arr ? s2p : s1p)[(size_t)nh * B_ * N_ + row0 + li] = s;
    }
}

// ---------------- K2a: brute-force rank + scatter + exps ----------------
// grid = B_*32 blocks, 512 threads; block ranks 64 elements, 8 threads/element.
__global__ __launch_bounds__(512) void k2a_rank(const float* __restrict__ s2p,
                                                float* __restrict__ ssort,
                                                int* __restrict__ sord,
                                                float* __restrict__ e2p,
                                                float* __restrict__ e2n) {
    __shared__ uint64_t keys[N_];   // 16 KB
    __shared__ int part[512];
    const int b = blockIdx.x >> 5, c = blockIdx.x & 31;
    const int tid = threadIdx.x;

    for (int t = tid; t < N_; t += 512) {
        float s2v = s2p[b * N_ + t] + s2p[(size_t)B_ * N_ + b * N_ + t];
        unsigned u = __float_as_uint(s2v);
        u = (u & 0x80000000u) ? ~u : (u | 0x80000000u);   // order-preserving map
        keys[t] = ((uint64_t)u << 16) | (unsigned)t;      // unique -> no ties
    }
    __syncthreads();

    const int le = tid & 63;
    const int e  = c * 64 + le;
    const int q  = tid >> 6;         // 0..7
    const uint64_t myk = keys[e];
    const uint64_t* kp = keys + q * 256;
    int cnt = 0;
#pragma unroll 8
    for (int kk = 0; kk < 256; ++kk) cnt += (int)(kp[kk] > myk);
    part[tid] = cnt;
    __syncthreads();

    if (tid < 64) {
        int rank = 0;
#pragma unroll
        for (int g = 0; g < 8; ++g) rank += part[tid + 64 * g];
        int ee = c * 64 + tid;
        float v = s2p[b * N_ + ee] + s2p[(size_t)B_ * N_ + b * N_ + ee];
        ssort[b * N_ + rank] = v;
        sord[b * N_ + rank]  = ee;
        e2p[b * N_ + rank] = expf(v);
        e2n[b * N_ + rank] = expf(ALPHA * v);
    }
}

// ---------------- KX: chunk 8-grain prefixes (blocks 0..255) ∪ scalar scan+cutoffs (256..263) ----------------
__global__ __launch_bounds__(512) void kx_scan(const float* __restrict__ Wh,
                                               const int* __restrict__ sord,
                                               const float* __restrict__ e2p,
                                               const float* __restrict__ e2n,
                                               const float* __restrict__ ssort,
                                               const float* __restrict__ s1p,
                                               float2* __restrict__ SUB,
                                               float2* __restrict__ DPN,
                                               int* __restrict__ kcut) {
    __shared__ float2 qt[4][FO];     // chunk part
    __shared__ float sv[N_];         // scan part
    __shared__ float2 wsum[8];
    const int tid = threadIdx.x;
    const int bid = blockIdx.x;

    if (bid < 256) {
        // one 64-chunk; q = tid>>7 owns 16 positions; grains of 8
        const int b = bid >> 5, ch = bid & 31;
        const int f = tid & 127, q = tid >> 7;
        const size_t base = (size_t)b * N_;
        const int ks = ch * CHUNK + q * 16;

        int ords[16]; float wp[16], wn[16], xv[16];
#pragma unroll
        for (int j = 0; j < 16; ++j) ords[j] = sord[base + ks + j];
#pragma unroll
        for (int j = 0; j < 16; ++j) { wp[j] = e2p[base + ks + j]; wn[j] = e2n[base + ks + j]; }
#pragma unroll
        for (int j = 0; j < 16; ++j) xv[j] = Wh[(base + ords[j]) * FO + f];

        float ap = 0.f, an = 0.f, apA = 0.f, anA = 0.f;
#pragma unroll
        for (int j = 0; j < 16; ++j) {
            ap += wp[j] * xv[j];
            an += wn[j] * xv[j];
            if (j == 7) { apA = ap; anA = an; }
        }
        qt[q][f] = make_float2(ap, an);
        __syncthreads();

        float op = 0.f, on = 0.f;
#pragma unroll
        for (int q2 = 0; q2 < 3; ++q2)
            if (q2 < q) { op += qt[q2][f].x; on += qt[q2][f].y; }

        const size_t sb = ((size_t)(b * NCHUNK + ch) * NGRAIN) * FO;
        SUB[sb + (2 * q + 0) * FO + f] = make_float2(apA + op, anA + on);
        SUB[sb + (2 * q + 1) * FO + f] = make_float2(ap + op, an + on);
    } else {
        // per-batch scalar scan + cutoffs
        const int b = bid - 256;
        const size_t base = (size_t)b * N_;

        float v[4], pv[4], nv[4], lp[4], ln[4];
        *(float4*)&v[0]  = *(const float4*)&ssort[base + tid * 4];
        *(float4*)&pv[0] = *(const float4*)&e2p[base + tid * 4];
        *(float4*)&nv[0] = *(const float4*)&e2n[base + tid * 4];
        float ap = 0.f, an = 0.f;
#pragma unroll
        for (int j = 0; j < 4; ++j) {
            sv[tid * 4 + j] = v[j];
            ap += pv[j]; lp[j] = ap;
            an += nv[j]; ln[j] = an;
        }

        float ip = ap, in2 = an;
        const int lane = tid & 63;
#pragma unroll
        for (int off = 1; off < 64; off <<= 1) {
            float tpv = __shfl_up(ip, off);
            float tnv = __shfl_up(in2, off);
            if (lane >= off) { ip += tpv; in2 += tnv; }
        }
        if (lane == 63) wsum[tid >> 6] = make_float2(ip, in2);
        __syncthreads();

        float basP = ip - ap, basN = in2 - an;
        const int w = tid >> 6;
#pragma unroll
        for (int w2 = 0; w2 < 7; ++w2)
            if (w2 < w) { basP += wsum[w2].x; basN += wsum[w2].y; }
#pragma unroll
        for (int j = 0; j < 4; ++j)
            DPN[base + tid * 4 + j] = make_float2(lp[j] + basP, ln[j] + basN);

        float tgt[4];
        int lo[4], hi[4];
#pragma unroll
        for (int r = 0; r < 4; ++r) {
            int row = tid + 512 * r;
            tgt[r] = -(s1p[base + row] + s1p[(size_t)B_ * N_ + base + row]);
            lo[r] = 0; hi[r] = N_;
        }
#pragma unroll
        for (int step = 0; step < 11; ++step) {
#pragma unroll
            for (int r = 0; r < 4; ++r) {
                int mid = (lo[r] + hi[r]) >> 1;
                bool live = lo[r] < hi[r];
                float pv2 = sv[mid & (N_ - 1)];
                bool cc = live && (pv2 >= tgt[r]);
                lo[r] = cc ? mid + 1 : lo[r];
                hi[r] = (live && !cc) ? mid : hi[r];
            }
        }
#pragma unroll
        for (int r = 0; r < 4; ++r) kcut[base + tid + 512 * r] = lo[r];
    }
}

// ---------------- K4: combine (chunk-total loop) + gather tail + elu ----------------
// grid = B_*N_/2 blocks, 256 threads (2 rows x 128 f)
__global__ __launch_bounds__(256) void k4_final(const float* __restrict__ s1p,
                                                const int* __restrict__ kcut,
                                                const float2* __restrict__ DPN,
                                                const float2* __restrict__ SUB,
                                                const float* __restrict__ Wh,
                                                const int* __restrict__ sord,
                                                const float* __restrict__ e2p,
                                                const float* __restrict__ e2n,
                                                float* __restrict__ out) {
    const int rowg = blockIdx.x * 2 + (threadIdx.x >> 7);
    const int f = threadIdx.x & 127;
    const int b = rowg >> 11;
    const size_t base = (size_t)b * N_;

    const float s1v = s1p[rowg] + s1p[(size_t)B_ * N_ + rowg];
    const int k = kcut[rowg];

    const float ep1 = expf(s1v), en1 = expf(ALPHA * s1v);
    float dp = 0.f, dn = 0.f;
    int c32 = -1, g8 = 0, km1 = -1;
    if (k > 0) {
        km1 = k - 1;
        c32 = km1 >> 6;            // CHUNK=64
        g8  = (km1 >> 3) & 7;      // grain within chunk
        float2 d = DPN[base + km1];
        dp = d.x; dn = d.y;
    }

    // one pass over 32 chunk totals: prefix below c32 AND grand total
    const float2* subb = SUB + (size_t)b * NCHUNK * NGRAIN * FO;
    float sp = 0.f, sn = 0.f, sntN = 0.f;
#pragma unroll 8
    for (int c = 0; c < NCHUNK; ++c) {
        float2 t = subb[((size_t)c * NGRAIN + 7) * FO + f];
        sntN += t.y;
        if (c < c32) { sp += t.x; sn += t.y; }
    }

    if (k > 0) {
        if (g8 > 0) {
            float2 su = subb[((size_t)c32 * NGRAIN + g8 - 1) * FO + f];
            sp += su.x; sn += su.y;
        }
        const int j0 = c32 * CHUNK + g8 * 8;
        for (int j = j0; j <= km1; ++j) {     // <=8 iters, wave-uniform
            int ord = sord[base + j];
            float wp = e2p[base + j];
            float wn = e2n[base + j];
            float x = Wh[(base + ord) * FO + f];
            sp += wp * x;
            sn += wn * x;
        }
    }
    const float dnt = DPN[base + N_ - 1].y;

    const float den = ep1 * dp + en1 * (dnt - dn);
    const float num = ep1 * sp + en1 * (sntN - sn);
    const float o = num / den;
    out[(size_t)rowg * FO + f] = (o > 0.f) ? o : (expf(o) - 1.f);
}

// ---------------- launch ----------------
extern "C" void kernel_launch(void* const* d_in, const int* in_sizes, int n_in,
                              void* d_out, int out_size, void* d_ws, size_t ws_size,
                              hipStream_t stream) {
    const float* h = (const float*)d_in[0];
    const float* W = (const float*)d_in[1];
    const float* a = (const float*)d_in[2];
    float* out = (float*)d_out;
    float* ws = (float*)d_ws;

    float*  Wh    = ws + OFF_WH;
    float*  s1p   = ws + OFF_S1P;
    float*  s2p   = ws + OFF_S2P;
    float*  ssort = ws + OFF_SSORT;
    int*    sord  = (int*)(ws + OFF_SORD);
    float*  e2p   = ws + OFF_E2P;
    float*  e2n   = ws + OFF_E2N;
    float2* DPN   = (float2*)(ws + OFF_DPN);
    int*    kcut  = (int*)(ws + OFF_KCUT);
    float2* SUB   = (float2*)(ws + OFF_SUB);

    k1_gemm<<<dim3(512), dim3(256), 0, stream>>>(h, W, a, Wh, s1p, s2p);
    k2a_rank<<<dim3(B_ * 32), dim3(512), 0, stream>>>(s2p, ssort, sord, e2p, e2n);
    kx_scan<<<dim3(264), dim3(512), 0, stream>>>(Wh, sord, e2p, e2n, ssort, s1p,
                                                 SUB, DPN, kcut);
    k4_final<<<dim3(B_ * N_ / 2), dim3(256), 0, stream>>>(s1p, kcut, DPN, SUB,
                                                          Wh, sord, e2p, e2n, out);
}

// Round 8
// 99.725 us; speedup vs baseline: 2.2402x; 1.0245x over previous
//
#include <hip/hip_runtime.h>
#include <math.h>
#include <stdint.h>

#define B_    8
#define N_    2048
#define FIN   256
#define FO    128
#define ALPHA 0.2f
#define NCHUNK 32
#define CHUNK  64    // N_/NCHUNK
#define NGRAIN 8     // grains per chunk, grain size 8

// ---------------- workspace layout (float elements) ----------------
static const size_t OFF_WH    = 0;                                    // B*N*FO
static const size_t OFF_S1P   = OFF_WH    + (size_t)B_*N_*FO;         // 2*B*N (two n-half partials)
static const size_t OFF_S2P   = OFF_S1P   + (size_t)2*B_*N_;          // 2*B*N
static const size_t OFF_SSORT = OFF_S2P   + (size_t)2*B_*N_;
static const size_t OFF_SORD  = OFF_SSORT + (size_t)B_*N_;
static const size_t OFF_E2P   = OFF_SORD  + (size_t)B_*N_;
static const size_t OFF_E2N   = OFF_E2P   + (size_t)B_*N_;
static const size_t OFF_DPN   = OFF_E2N   + (size_t)B_*N_;            // float2 * B*N
static const size_t OFF_KCUT  = OFF_DPN   + (size_t)2*B_*N_;
static const size_t OFF_SUB   = OFF_KCUT  + (size_t)B_*N_;            // float2 * B*NCHUNK*NGRAIN*FO

// ---------------- K1: Wh = h @ W (+ per-half partial s1,s2) ----------------
// 512 blocks: (mblk 0..255) x (nh 0..1). BM=64, BN=64. 256 threads, 4m x 4n.
__global__ __launch_bounds__(256) void k1_gemm(const float* __restrict__ h,
                                               const float* __restrict__ W,
                                               const float* __restrict__ a,
                                               float* __restrict__ Wh,
                                               float* __restrict__ s1p,
                                               float* __restrict__ s2p) {
    __shared__ __align__(16) float hS[32][68];   // [k][m] transposed, pad 68
    __shared__ __align__(16) float wS[32][64];   // [k][n-half]
    __shared__ float red[2][64][20];

    const int tid  = threadIdx.x;
    const int mblk = blockIdx.x >> 1, nh = blockIdx.x & 1;
    const int row0 = mblk * 64, col0 = nh * 64;
    const int tn = tid & 15;     // cols col0 + 4*tn .. +3
    const int tm = tid >> 4;     // rows 4*tm .. +3 (0..15)
    const int h_r = tid >> 2, h_c0 = (tid & 3) * 8;

    float acc[4][4];
#pragma unroll
    for (int m = 0; m < 4; ++m)
#pragma unroll
        for (int c = 0; c < 4; ++c) acc[m][c] = 0.f;

    float4 ha, hb, wreg[2];
    ha = *(const float4*)&h[(size_t)(row0 + h_r) * FIN + h_c0];
    hb = *(const float4*)&h[(size_t)(row0 + h_r) * FIN + h_c0 + 4];
#pragma unroll
    for (int p = 0; p < 2; ++p) {
        int idx = p * 256 + tid, kW = idx >> 4, n4 = (idx & 15) * 4;
        wreg[p] = *(const float4*)&W[(size_t)kW * FO + col0 + n4];
    }

    for (int kt = 0; kt < FIN; kt += 32) {
        hS[h_c0 + 0][h_r] = ha.x; hS[h_c0 + 1][h_r] = ha.y;
        hS[h_c0 + 2][h_r] = ha.z; hS[h_c0 + 3][h_r] = ha.w;
        hS[h_c0 + 4][h_r] = hb.x; hS[h_c0 + 5][h_r] = hb.y;
        hS[h_c0 + 6][h_r] = hb.z; hS[h_c0 + 7][h_r] = hb.w;
#pragma unroll
        for (int p = 0; p < 2; ++p) {
            int idx = p * 256 + tid, kW = idx >> 4, n4 = (idx & 15) * 4;
            *(float4*)&wS[kW][n4] = wreg[p];
        }
        __syncthreads();

        if (kt + 32 < FIN) {
            ha = *(const float4*)&h[(size_t)(row0 + h_r) * FIN + kt + 32 + h_c0];
            hb = *(const float4*)&h[(size_t)(row0 + h_r) * FIN + kt + 32 + h_c0 + 4];
#pragma unroll
            for (int p = 0; p < 2; ++p) {
                int idx = p * 256 + tid, kW = idx >> 4, n4 = (idx & 15) * 4;
                wreg[p] = *(const float4*)&W[(size_t)(kt + 32 + kW) * FO + col0 + n4];
            }
        }

#pragma unroll 8
        for (int kk = 0; kk < 32; ++kk) {
            float4 hv = *(float4*)&hS[kk][4 * tm];
            float4 wv = *(float4*)&wS[kk][4 * tn];
            float hm[4] = {hv.x, hv.y, hv.z, hv.w};
            float wn4[4] = {wv.x, wv.y, wv.z, wv.w};
#pragma unroll
            for (int m = 0; m < 4; ++m)
#pragma unroll
                for (int c = 0; c < 4; ++c)
                    acc[m][c] += hm[m] * wn4[c];
        }
        __syncthreads();
    }

#pragma unroll
    for (int m = 0; m < 4; ++m) {
        float4 o = make_float4(acc[m][0], acc[m][1], acc[m][2], acc[m][3]);
        *(float4*)&Wh[(size_t)(row0 + 4 * tm + m) * FO + col0 + 4 * tn] = o;
    }

    // per-half partial s1/s2
    float a1v[4], a2v[4];
#pragma unroll
    for (int c = 0; c < 4; ++c) {
        a1v[c] = a[col0 + 4 * tn + c];
        a2v[c] = a[FO + col0 + 4 * tn + c];
    }
#pragma unroll
    for (int m = 0; m < 4; ++m) {
        float p1 = 0.f, p2 = 0.f;
#pragma unroll
        for (int c = 0; c < 4; ++c) {
            p1 += acc[m][c] * a1v[c];
            p2 += acc[m][c] * a2v[c];
        }
        red[0][4 * tm + m][tn] = p1;
        red[1][4 * tm + m][tn] = p2;
    }
    __syncthreads();
    if (tid < 128) {
        int arr = tid >> 6, li = tid & 63;
        float s = 0.f;
#pragma unroll
        for (int g = 0; g < 16; ++g) s += red[arr][li][g];
        (arr ? s2p : s1p)[(size_t)nh * B_ * N_ + row0 + li] = s;
    }
}

// ---------------- K2a: brute-force rank + scatter + exps ----------------
__global__ __launch_bounds__(512) void k2a_rank(const float* __restrict__ s2p,
                                                float* __restrict__ ssort,
                                                int* __restrict__ sord,
                                                float* __restrict__ e2p,
                                                float* __restrict__ e2n) {
    __shared__ uint64_t keys[N_];   // 16 KB
    __shared__ int part[512];
    const int b = blockIdx.x >> 5, c = blockIdx.x & 31;
    const int tid = threadIdx.x;

    for (int t = tid; t < N_; t += 512) {
        float s2v = s2p[b * N_ + t] + s2p[(size_t)B_ * N_ + b * N_ + t];
        unsigned u = __float_as_uint(s2v);
        u = (u & 0x80000000u) ? ~u : (u | 0x80000000u);   // order-preserving map
        keys[t] = ((uint64_t)u << 16) | (unsigned)t;      // unique -> no ties
    }
    __syncthreads();

    const int le = tid & 63;
    const int e  = c * 64 + le;
    const int q  = tid >> 6;         // 0..7
    const uint64_t myk = keys[e];
    const uint64_t* kp = keys + q * 256;
    int cnt = 0;
#pragma unroll 8
    for (int kk = 0; kk < 256; ++kk) cnt += (int)(kp[kk] > myk);
    part[tid] = cnt;
    __syncthreads();

    if (tid < 64) {
        int rank = 0;
#pragma unroll
        for (int g = 0; g < 8; ++g) rank += part[tid + 64 * g];
        int ee = c * 64 + tid;
        float v = s2p[b * N_ + ee] + s2p[(size_t)B_ * N_ + b * N_ + ee];
        ssort[b * N_ + rank] = v;
        sord[b * N_ + rank]  = ee;
        e2p[b * N_ + rank] = expf(v);
        e2n[b * N_ + rank] = expf(ALPHA * v);
    }
}

// ---------------- KX: chunk 8-grain prefixes (blocks 0..255) ∪ scalar scan+cutoffs (256..263) ----------------
__global__ __launch_bounds__(512) void kx_scan(const float* __restrict__ Wh,
                                               const int* __restrict__ sord,
                                               const float* __restrict__ e2p,
                                               const float* __restrict__ e2n,
                                               const float* __restrict__ ssort,
                                               const float* __restrict__ s1p,
                                               float2* __restrict__ SUB,
                                               float2* __restrict__ DPN,
                                               int* __restrict__ kcut) {
    __shared__ float2 qt[4][FO];     // chunk part
    __shared__ float sv[N_];         // scan part
    __shared__ float2 wsum[8];
    const int tid = threadIdx.x;
    const int bid = blockIdx.x;

    if (bid < 256) {
        // one 64-chunk; q = tid>>7 owns 16 positions; grains of 8
        const int b = bid >> 5, ch = bid & 31;
        const int f = tid & 127, q = tid >> 7;
        const size_t base = (size_t)b * N_;
        const int ks = ch * CHUNK + q * 16;

        int ords[16]; float wp[16], wn[16], xv[16];
#pragma unroll
        for (int j = 0; j < 16; ++j) ords[j] = sord[base + ks + j];
#pragma unroll
        for (int j = 0; j < 16; ++j) { wp[j] = e2p[base + ks + j]; wn[j] = e2n[base + ks + j]; }
#pragma unroll
        for (int j = 0; j < 16; ++j) xv[j] = Wh[(base + ords[j]) * FO + f];

        float ap = 0.f, an = 0.f, apA = 0.f, anA = 0.f;
#pragma unroll
        for (int j = 0; j < 16; ++j) {
            ap += wp[j] * xv[j];
            an += wn[j] * xv[j];
            if (j == 7) { apA = ap; anA = an; }
        }
        qt[q][f] = make_float2(ap, an);
        __syncthreads();

        float op = 0.f, on = 0.f;
#pragma unroll
        for (int q2 = 0; q2 < 3; ++q2)
            if (q2 < q) { op += qt[q2][f].x; on += qt[q2][f].y; }

        const size_t sb = ((size_t)(b * NCHUNK + ch) * NGRAIN) * FO;
        SUB[sb + (2 * q + 0) * FO + f] = make_float2(apA + op, anA + on);
        SUB[sb + (2 * q + 1) * FO + f] = make_float2(ap + op, an + on);
    } else {
        // per-batch scalar scan + cutoffs
        const int b = bid - 256;
        const size_t base = (size_t)b * N_;

        float v[4], pv[4], nv[4], lp[4], ln[4];
        *(float4*)&v[0]  = *(const float4*)&ssort[base + tid * 4];
        *(float4*)&pv[0] = *(const float4*)&e2p[base + tid * 4];
        *(float4*)&nv[0] = *(const float4*)&e2n[base + tid * 4];
        float ap = 0.f, an = 0.f;
#pragma unroll
        for (int j = 0; j < 4; ++j) {
            sv[tid * 4 + j] = v[j];
            ap += pv[j]; lp[j] = ap;
            an += nv[j]; ln[j] = an;
        }

        float ip = ap, in2 = an;
        const int lane = tid & 63;
#pragma unroll
        for (int off = 1; off < 64; off <<= 1) {
            float tpv = __shfl_up(ip, off);
            float tnv = __shfl_up(in2, off);
            if (lane >= off) { ip += tpv; in2 += tnv; }
        }
        if (lane == 63) wsum[tid >> 6] = make_float2(ip, in2);
        __syncthreads();

        float basP = ip - ap, basN = in2 - an;
        const int w = tid >> 6;
#pragma unroll
        for (int w2 = 0; w2 < 7; ++w2)
            if (w2 < w) { basP += wsum[w2].x; basN += wsum[w2].y; }
#pragma unroll
        for (int j = 0; j < 4; ++j)
            DPN[base + tid * 4 + j] = make_float2(lp[j] + basP, ln[j] + basN);

        float tgt[4];
        int lo[4], hi[4];
#pragma unroll
        for (int r = 0; r < 4; ++r) {
            int row = tid + 512 * r;
            tgt[r] = -(s1p[base + row] + s1p[(size_t)B_ * N_ + base + row]);
            lo[r] = 0; hi[r] = N_;
        }
#pragma unroll
        for (int step = 0; step < 11; ++step) {
#pragma unroll
            for (int r = 0; r < 4; ++r) {
                int mid = (lo[r] + hi[r]) >> 1;
                bool live = lo[r] < hi[r];
                float pv2 = sv[mid & (N_ - 1)];
                bool cc = live && (pv2 >= tgt[r]);
                lo[r] = cc ? mid + 1 : lo[r];
                hi[r] = (live && !cc) ? mid : hi[r];
            }
        }
#pragma unroll
        for (int r = 0; r < 4; ++r) kcut[base + tid + 512 * r] = lo[r];
    }
}

// ---------------- K4: per-32-row block: LDS chunk-offset scan + combine + tail + elu ----------------
// grid = B_*N_/32 = 512 blocks, 256 threads (2 rows x 128 f per iteration, 16 iters)
__global__ __launch_bounds__(256) void k4_final(const float* __restrict__ s1p,
                                                const int* __restrict__ kcut,
                                                const float2* __restrict__ DPN,
                                                const float2* __restrict__ SUB,
                                                const float* __restrict__ Wh,
                                                const int* __restrict__ sord,
                                                const float* __restrict__ e2p,
                                                const float* __restrict__ e2n,
                                                float* __restrict__ out) {
    __shared__ float2 ct[NCHUNK][FO];        // 32 KB -> becomes exclusive prefix
    __shared__ float2 halfTot[2][FO];
    __shared__ float sntN_lds[FO];

    const int bid = blockIdx.x;
    const int b   = bid >> 6;                // 64 blocks per batch
    const int r0  = (bid & 63) * 32;         // first row of this block
    const int tid = threadIdx.x;
    const int f = tid & 127, hh = tid >> 7;
    const size_t base = (size_t)b * N_;
    const float2* subb = SUB + (size_t)b * NCHUNK * NGRAIN * FO;

    // 1) load 32 chunk totals (grain 7 of each chunk)
    for (int idx = tid; idx < NCHUNK * FO; idx += 256) {
        int c = idx >> 7, ff = idx & 127;
        ct[c][ff] = subb[((size_t)c * NGRAIN + 7) * FO + ff];
    }
    __syncthreads();

    // 2) in-place exclusive scan over chunks (2 halves of 16 + fixup)
    float rp = 0.f, rn = 0.f;
    for (int c = hh * 16; c < hh * 16 + 16; ++c) {
        float2 t = ct[c][f];
        ct[c][f] = make_float2(rp, rn);
        rp += t.x; rn += t.y;
    }
    halfTot[hh][f] = make_float2(rp, rn);
    __syncthreads();
    if (hh == 1) {
        float2 h0 = halfTot[0][f];
        for (int c = 16; c < 32; ++c) {
            float2 t = ct[c][f];
            ct[c][f] = make_float2(t.x + h0.x, t.y + h0.y);
        }
    }
    if (tid < FO) sntN_lds[tid] = halfTot[0][tid].y + halfTot[1][tid].y;
    __syncthreads();

    const float dnt = DPN[base + N_ - 1].y;

    // 3) 16 row-pair iterations
    for (int it = 0; it < 16; ++it) {
        const int row  = r0 + it * 2 + hh;
        const int rowg = b * N_ + row;

        const float s1v = s1p[rowg] + s1p[(size_t)B_ * N_ + rowg];
        const int k = kcut[base + row];

        const float ep1 = expf(s1v), en1 = expf(ALPHA * s1v);
        float dp = 0.f, dn = 0.f, sp = 0.f, sn = 0.f;
        if (k > 0) {
            const int km1 = k - 1;
            const int c32 = km1 >> 6;          // CHUNK=64
            const int g8  = (km1 >> 3) & 7;
            float2 d = DPN[base + km1];
            dp = d.x; dn = d.y;
            float2 o = ct[c32][f];
            sp = o.x; sn = o.y;
            if (g8 > 0) {
                float2 su = subb[((size_t)c32 * NGRAIN + g8 - 1) * FO + f];
                sp += su.x; sn += su.y;
            }
            const int j0 = c32 * CHUNK + g8 * 8;
            for (int j = j0; j <= km1; ++j) {   // <=8 iters, wave-uniform
                int ord = sord[base + j];
                float wp = e2p[base + j];
                float wn = e2n[base + j];
                float x = Wh[(base + ord) * FO + f];
                sp += wp * x;
                sn += wn * x;
            }
        }
        const float sntN = sntN_lds[f];
        const float den = ep1 * dp + en1 * (dnt - dn);
        const float num = ep1 * sp + en1 * (sntN - sn);
        const float o = num / den;
        out[(size_t)rowg * FO + f] = (o > 0.f) ? o : (expf(o) - 1.f);
    }
}

// ---------------- launch ----------------
extern "C" void kernel_launch(void* const* d_in, const int* in_sizes, int n_in,
                              void* d_out, int out_size, void* d_ws, size_t ws_size,
                              hipStream_t stream) {
    const float* h = (const float*)d_in[0];
    const float* W = (const float*)d_in[1];
    const float* a = (const float*)d_in[2];
    float* out = (float*)d_out;
    float* ws = (float*)d_ws;

    float*  Wh    = ws + OFF_WH;
    float*  s1p   = ws + OFF_S1P;
    float*  s2p   = ws + OFF_S2P;
    float*  ssort = ws + OFF_SSORT;
    int*    sord  = (int*)(ws + OFF_SORD);
    float*  e2p   = ws + OFF_E2P;
    float*  e2n   = ws + OFF_E2N;
    float2* DPN   = (float2*)(ws + OFF_DPN);
    int*    kcut  = (int*)(ws + OFF_KCUT);
    float2* SUB   = (float2*)(ws + OFF_SUB);

    k1_gemm<<<dim3(512), dim3(256), 0, stream>>>(h, W, a, Wh, s1p, s2p);
    k2a_rank<<<dim3(B_ * 32), dim3(512), 0, stream>>>(s2p, ssort, sord, e2p, e2n);
    kx_scan<<<dim3(264), dim3(512), 0, stream>>>(Wh, sord, e2p, e2n, ssort, s1p,
                                                 SUB, DPN, kcut);
    k4_final<<<dim3(512), dim3(256), 0, stream>>>(s1p, kcut, DPN, SUB,
                                                  Wh, sord, e2p, e2n, out);
}

// Round 9
// 60.883 us; speedup vs baseline: 3.6694x; 1.6380x over previous
//
#include <hip/hip_runtime.h>
#include <math.h>
#include <stdint.h>

#define B_    8
#define N_    2048
#define FIN   256
#define FO    128
#define ALPHA 0.2f
#define NCHUNK 32
#define CHUNK  64    // N_/NCHUNK
#define NGRAIN 8     // grains per chunk, grain size 8

// ---------------- workspace layout (float elements) ----------------
static const size_t OFF_WH    = 0;                                    // B*N*FO
static const size_t OFF_S1P   = OFF_WH    + (size_t)B_*N_*FO;         // 2*B*N (two n-half partials)
static const size_t OFF_S2P   = OFF_S1P   + (size_t)2*B_*N_;          // 2*B*N
static const size_t OFF_SSORT = OFF_S2P   + (size_t)2*B_*N_;
static const size_t OFF_SORD  = OFF_SSORT + (size_t)B_*N_;
static const size_t OFF_E2P   = OFF_SORD  + (size_t)B_*N_;
static const size_t OFF_E2N   = OFF_E2P   + (size_t)B_*N_;
static const size_t OFF_DPN   = OFF_E2N   + (size_t)B_*N_;            // float2 * B*N
static const size_t OFF_KCUT  = OFF_DPN   + (size_t)2*B_*N_;
static const size_t OFF_SUB   = OFF_KCUT  + (size_t)B_*N_;            // float2 * B*NCHUNK*NGRAIN*FO

// ---------------- K1: Wh = h @ W (+ per-half partial s1,s2) ----------------
// 512 blocks: (mblk 0..255) x (nh 0..1). BM=64, BN=64. 256 threads, 4m x 4n.
__global__ __launch_bounds__(256) void k1_gemm(const float* __restrict__ h,
                                               const float* __restrict__ W,
                                               const float* __restrict__ a,
                                               float* __restrict__ Wh,
                                               float* __restrict__ s1p,
                                               float* __restrict__ s2p) {
    __shared__ __align__(16) float hS[32][68];   // [k][m] transposed, pad 68
    __shared__ __align__(16) float wS[32][64];   // [k][n-half]
    __shared__ float red[2][64][20];

    const int tid  = threadIdx.x;
    const int mblk = blockIdx.x >> 1, nh = blockIdx.x & 1;
    const int row0 = mblk * 64, col0 = nh * 64;
    const int tn = tid & 15;     // cols col0 + 4*tn .. +3
    const int tm = tid >> 4;     // rows 4*tm .. +3 (0..15)
    const int h_r = tid >> 2, h_c0 = (tid & 3) * 8;

    float acc[4][4];
#pragma unroll
    for (int m = 0; m < 4; ++m)
#pragma unroll
        for (int c = 0; c < 4; ++c) acc[m][c] = 0.f;

    float4 ha, hb, wreg[2];
    ha = *(const float4*)&h[(size_t)(row0 + h_r) * FIN + h_c0];
    hb = *(const float4*)&h[(size_t)(row0 + h_r) * FIN + h_c0 + 4];
#pragma unroll
    for (int p = 0; p < 2; ++p) {
        int idx = p * 256 + tid, kW = idx >> 4, n4 = (idx & 15) * 4;
        wreg[p] = *(const float4*)&W[(size_t)kW * FO + col0 + n4];
    }

    for (int kt = 0; kt < FIN; kt += 32) {
        hS[h_c0 + 0][h_r] = ha.x; hS[h_c0 + 1][h_r] = ha.y;
        hS[h_c0 + 2][h_r] = ha.z; hS[h_c0 + 3][h_r] = ha.w;
        hS[h_c0 + 4][h_r] = hb.x; hS[h_c0 + 5][h_r] = hb.y;
        hS[h_c0 + 6][h_r] = hb.z; hS[h_c0 + 7][h_r] = hb.w;
#pragma unroll
        for (int p = 0; p < 2; ++p) {
            int idx = p * 256 + tid, kW = idx >> 4, n4 = (idx & 15) * 4;
            *(float4*)&wS[kW][n4] = wreg[p];
        }
        __syncthreads();

        if (kt + 32 < FIN) {
            ha = *(const float4*)&h[(size_t)(row0 + h_r) * FIN + kt + 32 + h_c0];
            hb = *(const float4*)&h[(size_t)(row0 + h_r) * FIN + kt + 32 + h_c0 + 4];
#pragma unroll
            for (int p = 0; p < 2; ++p) {
                int idx = p * 256 + tid, kW = idx >> 4, n4 = (idx & 15) * 4;
                wreg[p] = *(const float4*)&W[(size_t)(kt + 32 + kW) * FO + col0 + n4];
            }
        }

#pragma unroll 8
        for (int kk = 0; kk < 32; ++kk) {
            float4 hv = *(float4*)&hS[kk][4 * tm];
            float4 wv = *(float4*)&wS[kk][4 * tn];
            float hm[4] = {hv.x, hv.y, hv.z, hv.w};
            float wn4[4] = {wv.x, wv.y, wv.z, wv.w};
#pragma unroll
            for (int m = 0; m < 4; ++m)
#pragma unroll
                for (int c = 0; c < 4; ++c)
                    acc[m][c] += hm[m] * wn4[c];
        }
        __syncthreads();
    }

#pragma unroll
    for (int m = 0; m < 4; ++m) {
        float4 o = make_float4(acc[m][0], acc[m][1], acc[m][2], acc[m][3]);
        *(float4*)&Wh[(size_t)(row0 + 4 * tm + m) * FO + col0 + 4 * tn] = o;
    }

    // per-half partial s1/s2
    float a1v[4], a2v[4];
#pragma unroll
    for (int c = 0; c < 4; ++c) {
        a1v[c] = a[col0 + 4 * tn + c];
        a2v[c] = a[FO + col0 + 4 * tn + c];
    }
#pragma unroll
    for (int m = 0; m < 4; ++m) {
        float p1 = 0.f, p2 = 0.f;
#pragma unroll
        for (int c = 0; c < 4; ++c) {
            p1 += acc[m][c] * a1v[c];
            p2 += acc[m][c] * a2v[c];
        }
        red[0][4 * tm + m][tn] = p1;
        red[1][4 * tm + m][tn] = p2;
    }
    __syncthreads();
    if (tid < 128) {
        int arr = tid >> 6, li = tid & 63;
        float s = 0.f;
#pragma unroll
        for (int g = 0; g < 16; ++g) s += red[arr][li][g];
        (arr ? s2p : s1p)[(size_t)nh * B_ * N_ + row0 + li] = s;
    }
}

// ---------------- K2a: brute-force rank + scatter + exps ----------------
__global__ __launch_bounds__(512) void k2a_rank(const float* __restrict__ s2p,
                                                float* __restrict__ ssort,
                                                int* __restrict__ sord,
                                                float* __restrict__ e2p,
                                                float* __restrict__ e2n) {
    __shared__ uint64_t keys[N_];   // 16 KB
    __shared__ int part[512];
    const int b = blockIdx.x >> 5, c = blockIdx.x & 31;
    const int tid = threadIdx.x;

    for (int t = tid; t < N_; t += 512) {
        float s2v = s2p[b * N_ + t] + s2p[(size_t)B_ * N_ + b * N_ + t];
        unsigned u = __float_as_uint(s2v);
        u = (u & 0x80000000u) ? ~u : (u | 0x80000000u);   // order-preserving map
        keys[t] = ((uint64_t)u << 16) | (unsigned)t;      // unique -> no ties
    }
    __syncthreads();

    const int le = tid & 63;
    const int e  = c * 64 + le;
    const int q  = tid >> 6;         // 0..7
    const uint64_t myk = keys[e];
    const uint64_t* kp = keys + q * 256;
    int cnt = 0;
#pragma unroll 8
    for (int kk = 0; kk < 256; ++kk) cnt += (int)(kp[kk] > myk);
    part[tid] = cnt;
    __syncthreads();

    if (tid < 64) {
        int rank = 0;
#pragma unroll
        for (int g = 0; g < 8; ++g) rank += part[tid + 64 * g];
        int ee = c * 64 + tid;
        float v = s2p[b * N_ + ee] + s2p[(size_t)B_ * N_ + b * N_ + ee];
        ssort[b * N_ + rank] = v;
        sord[b * N_ + rank]  = ee;
        e2p[b * N_ + rank] = expf(v);
        e2n[b * N_ + rank] = expf(ALPHA * v);
    }
}

// ---------------- KX: chunk 8-grain prefixes (blocks 0..255) ∪ scalar scan+cutoffs (256..263) ----------------
__global__ __launch_bounds__(512) void kx_scan(const float* __restrict__ Wh,
                                               const int* __restrict__ sord,
                                               const float* __restrict__ e2p,
                                               const float* __restrict__ e2n,
                                               const float* __restrict__ ssort,
                                               const float* __restrict__ s1p,
                                               float2* __restrict__ SUB,
                                               float2* __restrict__ DPN,
                                               int* __restrict__ kcut) {
    __shared__ float2 qt[4][FO];     // chunk part
    __shared__ float sv[N_];         // scan part
    __shared__ float2 wsum[8];
    const int tid = threadIdx.x;
    const int bid = blockIdx.x;

    if (bid < 256) {
        // one 64-chunk; q = tid>>7 owns 16 positions; grains of 8
        const int b = bid >> 5, ch = bid & 31;
        const int f = tid & 127, q = tid >> 7;
        const size_t base = (size_t)b * N_;
        const int ks = ch * CHUNK + q * 16;

        int ords[16]; float wp[16], wn[16], xv[16];
#pragma unroll
        for (int j = 0; j < 16; ++j) ords[j] = sord[base + ks + j];
#pragma unroll
        for (int j = 0; j < 16; ++j) { wp[j] = e2p[base + ks + j]; wn[j] = e2n[base + ks + j]; }
#pragma unroll
        for (int j = 0; j < 16; ++j) xv[j] = Wh[(base + ords[j]) * FO + f];

        float ap = 0.f, an = 0.f, apA = 0.f, anA = 0.f;
#pragma unroll
        for (int j = 0; j < 16; ++j) {
            ap += wp[j] * xv[j];
            an += wn[j] * xv[j];
            if (j == 7) { apA = ap; anA = an; }
        }
        qt[q][f] = make_float2(ap, an);
        __syncthreads();

        float op = 0.f, on = 0.f;
#pragma unroll
        for (int q2 = 0; q2 < 3; ++q2)
            if (q2 < q) { op += qt[q2][f].x; on += qt[q2][f].y; }

        const size_t sb = ((size_t)(b * NCHUNK + ch) * NGRAIN) * FO;
        SUB[sb + (2 * q + 0) * FO + f] = make_float2(apA + op, anA + on);
        SUB[sb + (2 * q + 1) * FO + f] = make_float2(ap + op, an + on);
    } else {
        // per-batch scalar scan + cutoffs
        const int b = bid - 256;
        const size_t base = (size_t)b * N_;

        float v[4], pv[4], nv[4], lp[4], ln[4];
        *(float4*)&v[0]  = *(const float4*)&ssort[base + tid * 4];
        *(float4*)&pv[0] = *(const float4*)&e2p[base + tid * 4];
        *(float4*)&nv[0] = *(const float4*)&e2n[base + tid * 4];
        float ap = 0.f, an = 0.f;
#pragma unroll
        for (int j = 0; j < 4; ++j) {
            sv[tid * 4 + j] = v[j];
            ap += pv[j]; lp[j] = ap;
            an += nv[j]; ln[j] = an;
        }

        float ip = ap, in2 = an;
        const int lane = tid & 63;
#pragma unroll
        for (int off = 1; off < 64; off <<= 1) {
            float tpv = __shfl_up(ip, off);
            float tnv = __shfl_up(in2, off);
            if (lane >= off) { ip += tpv; in2 += tnv; }
        }
        if (lane == 63) wsum[tid >> 6] = make_float2(ip, in2);
        __syncthreads();

        float basP = ip - ap, basN = in2 - an;
        const int w = tid >> 6;
#pragma unroll
        for (int w2 = 0; w2 < 7; ++w2)
            if (w2 < w) { basP += wsum[w2].x; basN += wsum[w2].y; }
#pragma unroll
        for (int j = 0; j < 4; ++j)
            DPN[base + tid * 4 + j] = make_float2(lp[j] + basP, ln[j] + basN);

        float tgt[4];
        int lo[4], hi[4];
#pragma unroll
        for (int r = 0; r < 4; ++r) {
            int row = tid + 512 * r;
            tgt[r] = -(s1p[base + row] + s1p[(size_t)B_ * N_ + base + row]);
            lo[r] = 0; hi[r] = N_;
        }
#pragma unroll
        for (int step = 0; step < 11; ++step) {
#pragma unroll
            for (int r = 0; r < 4; ++r) {
                int mid = (lo[r] + hi[r]) >> 1;
                bool live = lo[r] < hi[r];
                float pv2 = sv[mid & (N_ - 1)];
                bool cc = live && (pv2 >= tgt[r]);
                lo[r] = cc ? mid + 1 : lo[r];
                hi[r] = (live && !cc) ? mid : hi[r];
            }
        }
#pragma unroll
        for (int r = 0; r < 4; ++r) kcut[base + tid + 512 * r] = lo[r];
    }
}

// ---------------- K4: per-32-row block, 512 threads, latency-tolerant tail ----------------
// grid = 512 blocks, 512 threads (4 rows x 128 f per iteration, 8 iters)
__global__ __launch_bounds__(512) void k4_final(const float* __restrict__ s1p,
                                                const int* __restrict__ kcut,
                                                const float2* __restrict__ DPN,
                                                const float2* __restrict__ SUB,
                                                const float* __restrict__ Wh,
                                                const int* __restrict__ sord,
                                                const float* __restrict__ e2p,
                                                const float* __restrict__ e2n,
                                                float* __restrict__ out) {
    __shared__ float2 ct[NCHUNK][FO];        // 32 KB -> becomes exclusive prefix
    __shared__ float2 qTot[4][FO];           // 4 KB
    __shared__ float sntN_lds[FO];
    __shared__ float s1_lds[32];
    __shared__ int   k_lds[32];

    const int bid = blockIdx.x;
    const int b   = bid >> 6;                // 64 blocks per batch
    const int r0  = (bid & 63) * 32;         // first row of this block
    const int tid = threadIdx.x;
    const int f = tid & 127, rr = tid >> 7;  // rr = 0..3
    const size_t base = (size_t)b * N_;
    const float2* subb = SUB + (size_t)b * NCHUNK * NGRAIN * FO;

    // 1) load 32 chunk totals (grain 7 of each chunk)
    for (int idx = tid; idx < NCHUNK * FO; idx += 512) {
        int c = idx >> 7, ff = idx & 127;
        ct[c][ff] = subb[((size_t)c * NGRAIN + 7) * FO + ff];
    }
    // stage per-row scalars
    if (tid < 32) {
        int row = r0 + tid;
        k_lds[tid] = kcut[base + row];
        s1_lds[tid] = s1p[base + row] + s1p[(size_t)B_ * N_ + base + row];
    }
    __syncthreads();

    // 2) exclusive scan over chunks: 4 quarters of 8 + fixup
    float rp = 0.f, rn = 0.f;
    for (int c = rr * 8; c < rr * 8 + 8; ++c) {
        float2 t = ct[c][f];
        ct[c][f] = make_float2(rp, rn);
        rp += t.x; rn += t.y;
    }
    qTot[rr][f] = make_float2(rp, rn);
    __syncthreads();
    float addP = 0.f, addN = 0.f;
#pragma unroll
    for (int q2 = 0; q2 < 3; ++q2)
        if (q2 < rr) { addP += qTot[q2][f].x; addN += qTot[q2][f].y; }
    if (rr > 0) {
        for (int c = rr * 8; c < rr * 8 + 8; ++c) {
            float2 t = ct[c][f];
            ct[c][f] = make_float2(t.x + addP, t.y + addN);
        }
    }
    if (tid < FO)
        sntN_lds[tid] = qTot[0][tid].y + qTot[1][tid].y + qTot[2][tid].y + qTot[3][tid].y;
    __syncthreads();

    const float dnt = DPN[base + N_ - 1].y;
    const float sntN = sntN_lds[f];

    // 3) 8 iterations x 4 rows; fixed-trip masked gather for latency overlap
#pragma unroll 2
    for (int it = 0; it < 8; ++it) {
        const int lr   = it * 4 + rr;        // local row 0..31
        const int row  = r0 + lr;
        const float s1v = s1_lds[lr];
        const int k = k_lds[lr];

        const float ep1 = expf(s1v), en1 = expf(ALPHA * s1v);
        float dp = 0.f, dn = 0.f, sp = 0.f, sn = 0.f;
        if (k > 0) {
            const int km1 = k - 1;
            const int c32 = km1 >> 6;          // CHUNK=64
            const int g8  = (km1 >> 3) & 7;
            float2 d = DPN[base + km1];
            dp = d.x; dn = d.y;
            float2 o = ct[c32][f];
            sp = o.x; sn = o.y;
            if (g8 > 0) {
                float2 su = subb[((size_t)c32 * NGRAIN + g8 - 1) * FO + f];
                sp += su.x; sn += su.y;
            }
            const int j0 = c32 * CHUNK + g8 * 8;
            // fixed 8-trip masked gather: all loads independent & in flight
            int   jj[8]; float wpv[8], wnv[8];
            int   ords[8];
#pragma unroll
            for (int t = 0; t < 8; ++t) jj[t] = (j0 + t <= km1) ? (j0 + t) : km1;
#pragma unroll
            for (int t = 0; t < 8; ++t) ords[t] = sord[base + jj[t]];
#pragma unroll
            for (int t = 0; t < 8; ++t) {
                bool act = (j0 + t <= km1);
                wpv[t] = act ? e2p[base + jj[t]] : 0.f;
                wnv[t] = act ? e2n[base + jj[t]] : 0.f;
            }
#pragma unroll
            for (int t = 0; t < 8; ++t) {
                float x = Wh[(base + ords[t]) * FO + f];
                sp += wpv[t] * x;
                sn += wnv[t] * x;
            }
        }
        const float den = ep1 * dp + en1 * (dnt - dn);
        const float num = ep1 * sp + en1 * (sntN - sn);
        const float o = num / den;
        out[((size_t)b * N_ + row) * FO + f] = (o > 0.f) ? o : (expf(o) - 1.f);
    }
}

// ---------------- launch ----------------
extern "C" void kernel_launch(void* const* d_in, const int* in_sizes, int n_in,
                              void* d_out, int out_size, void* d_ws, size_t ws_size,
                              hipStream_t stream) {
    const float* h = (const float*)d_in[0];
    const float* W = (const float*)d_in[1];
    const float* a = (const float*)d_in[2];
    float* out = (float*)d_out;
    float* ws = (float*)d_ws;

    float*  Wh    = ws + OFF_WH;
    float*  s1p   = ws + OFF_S1P;
    float*  s2p   = ws + OFF_S2P;
    float*  ssort = ws + OFF_SSORT;
    int*    sord  = (int*)(ws + OFF_SORD);
    float*  e2p   = ws + OFF_E2P;
    float*  e2n   = ws + OFF_E2N;
    float2* DPN   = (float2*)(ws + OFF_DPN);
    int*    kcut  = (int*)(ws + OFF_KCUT);
    float2* SUB   = (float2*)(ws + OFF_SUB);

    k1_gemm<<<dim3(512), dim3(256), 0, stream>>>(h, W, a, Wh, s1p, s2p);
    k2a_rank<<<dim3(B_ * 32), dim3(512), 0, stream>>>(s2p, ssort, sord, e2p, e2n);
    kx_scan<<<dim3(264), dim3(512), 0, stream>>>(Wh, sord, e2p, e2n, ssort, s1p,
                                                 SUB, DPN, kcut);
    k4_final<<<dim3(512), dim3(512), 0, stream>>>(s1p, kcut, DPN, SUB,
                                                  Wh, sord, e2p, e2n, out);
}

// Round 10
// 53.047 us; speedup vs baseline: 4.2115x; 1.1477x over previous
//
#include <hip/hip_runtime.h>
#include <math.h>
#include <stdint.h>

#define B_    8
#define N_    2048
#define FIN   256
#define FO    128
#define ALPHA 0.2f
#define NCHUNK 32
#define CHUNK  64    // N_/NCHUNK

// ---------------- workspace layout (float elements) ----------------
static const size_t OFF_WH    = 0;                                    // B*N*FO
static const size_t OFF_S1P   = OFF_WH    + (size_t)B_*N_*FO;         // 2*B*N (two n-half partials)
static const size_t OFF_S2P   = OFF_S1P   + (size_t)2*B_*N_;          // 2*B*N
static const size_t OFF_SSORT = OFF_S2P   + (size_t)2*B_*N_;
static const size_t OFF_SORD  = OFF_SSORT + (size_t)B_*N_;
static const size_t OFF_E2P   = OFF_SORD  + (size_t)B_*N_;
static const size_t OFF_E2N   = OFF_E2P   + (size_t)B_*N_;
static const size_t OFF_DPN   = OFF_E2N   + (size_t)B_*N_;            // float2 * B*N
static const size_t OFF_KCUT  = OFF_DPN   + (size_t)2*B_*N_;
static const size_t OFF_SPN   = OFF_KCUT  + (size_t)B_*N_;            // float2 * B*N*FO (chunk-local prefixes)

// ---------------- K1: Wh = h @ W (+ per-half partial s1,s2) ----------------
// 512 blocks: (mblk 0..255) x (nh 0..1). BM=64, BN=64. 256 threads, 4m x 4n.
__global__ __launch_bounds__(256) void k1_gemm(const float* __restrict__ h,
                                               const float* __restrict__ W,
                                               const float* __restrict__ a,
                                               float* __restrict__ Wh,
                                               float* __restrict__ s1p,
                                               float* __restrict__ s2p) {
    __shared__ __align__(16) float hS[32][68];   // [k][m] transposed, pad 68
    __shared__ __align__(16) float wS[32][64];   // [k][n-half]
    __shared__ float red[2][64][20];

    const int tid  = threadIdx.x;
    const int mblk = blockIdx.x >> 1, nh = blockIdx.x & 1;
    const int row0 = mblk * 64, col0 = nh * 64;
    const int tn = tid & 15;     // cols col0 + 4*tn .. +3
    const int tm = tid >> 4;     // rows 4*tm .. +3 (0..15)
    const int h_r = tid >> 2, h_c0 = (tid & 3) * 8;

    float acc[4][4];
#pragma unroll
    for (int m = 0; m < 4; ++m)
#pragma unroll
        for (int c = 0; c < 4; ++c) acc[m][c] = 0.f;

    float4 ha, hb, wreg[2];
    ha = *(const float4*)&h[(size_t)(row0 + h_r) * FIN + h_c0];
    hb = *(const float4*)&h[(size_t)(row0 + h_r) * FIN + h_c0 + 4];
#pragma unroll
    for (int p = 0; p < 2; ++p) {
        int idx = p * 256 + tid, kW = idx >> 4, n4 = (idx & 15) * 4;
        wreg[p] = *(const float4*)&W[(size_t)kW * FO + col0 + n4];
    }

    for (int kt = 0; kt < FIN; kt += 32) {
        hS[h_c0 + 0][h_r] = ha.x; hS[h_c0 + 1][h_r] = ha.y;
        hS[h_c0 + 2][h_r] = ha.z; hS[h_c0 + 3][h_r] = ha.w;
        hS[h_c0 + 4][h_r] = hb.x; hS[h_c0 + 5][h_r] = hb.y;
        hS[h_c0 + 6][h_r] = hb.z; hS[h_c0 + 7][h_r] = hb.w;
#pragma unroll
        for (int p = 0; p < 2; ++p) {
            int idx = p * 256 + tid, kW = idx >> 4, n4 = (idx & 15) * 4;
            *(float4*)&wS[kW][n4] = wreg[p];
        }
        __syncthreads();

        if (kt + 32 < FIN) {
            ha = *(const float4*)&h[(size_t)(row0 + h_r) * FIN + kt + 32 + h_c0];
            hb = *(const float4*)&h[(size_t)(row0 + h_r) * FIN + kt + 32 + h_c0 + 4];
#pragma unroll
            for (int p = 0; p < 2; ++p) {
                int idx = p * 256 + tid, kW = idx >> 4, n4 = (idx & 15) * 4;
                wreg[p] = *(const float4*)&W[(size_t)(kt + 32 + kW) * FO + col0 + n4];
            }
        }

#pragma unroll 8
        for (int kk = 0; kk < 32; ++kk) {
            float4 hv = *(float4*)&hS[kk][4 * tm];
            float4 wv = *(float4*)&wS[kk][4 * tn];
            float hm[4] = {hv.x, hv.y, hv.z, hv.w};
            float wn4[4] = {wv.x, wv.y, wv.z, wv.w};
#pragma unroll
            for (int m = 0; m < 4; ++m)
#pragma unroll
                for (int c = 0; c < 4; ++c)
                    acc[m][c] += hm[m] * wn4[c];
        }
        __syncthreads();
    }

#pragma unroll
    for (int m = 0; m < 4; ++m) {
        float4 o = make_float4(acc[m][0], acc[m][1], acc[m][2], acc[m][3]);
        *(float4*)&Wh[(size_t)(row0 + 4 * tm + m) * FO + col0 + 4 * tn] = o;
    }

    // per-half partial s1/s2
    float a1v[4], a2v[4];
#pragma unroll
    for (int c = 0; c < 4; ++c) {
        a1v[c] = a[col0 + 4 * tn + c];
        a2v[c] = a[FO + col0 + 4 * tn + c];
    }
#pragma unroll
    for (int m = 0; m < 4; ++m) {
        float p1 = 0.f, p2 = 0.f;
#pragma unroll
        for (int c = 0; c < 4; ++c) {
            p1 += acc[m][c] * a1v[c];
            p2 += acc[m][c] * a2v[c];
        }
        red[0][4 * tm + m][tn] = p1;
        red[1][4 * tm + m][tn] = p2;
    }
    __syncthreads();
    if (tid < 128) {
        int arr = tid >> 6, li = tid & 63;
        float s = 0.f;
#pragma unroll
        for (int g = 0; g < 16; ++g) s += red[arr][li][g];
        (arr ? s2p : s1p)[(size_t)nh * B_ * N_ + row0 + li] = s;
    }
}

// ---------------- K2a: brute-force rank + scatter + exps ----------------
__global__ __launch_bounds__(512) void k2a_rank(const float* __restrict__ s2p,
                                                float* __restrict__ ssort,
                                                int* __restrict__ sord,
                                                float* __restrict__ e2p,
                                                float* __restrict__ e2n) {
    __shared__ uint64_t keys[N_];   // 16 KB
    __shared__ int part[512];
    const int b = blockIdx.x >> 5, c = blockIdx.x & 31;
    const int tid = threadIdx.x;

    for (int t = tid; t < N_; t += 512) {
        float s2v = s2p[b * N_ + t] + s2p[(size_t)B_ * N_ + b * N_ + t];
        unsigned u = __float_as_uint(s2v);
        u = (u & 0x80000000u) ? ~u : (u | 0x80000000u);   // order-preserving map
        keys[t] = ((uint64_t)u << 16) | (unsigned)t;      // unique -> no ties
    }
    __syncthreads();

    const int le = tid & 63;
    const int e  = c * 64 + le;
    const int q  = tid >> 6;         // 0..7
    const uint64_t myk = keys[e];
    const uint64_t* kp = keys + q * 256;
    int cnt = 0;
#pragma unroll 8
    for (int kk = 0; kk < 256; ++kk) cnt += (int)(kp[kk] > myk);
    part[tid] = cnt;
    __syncthreads();

    if (tid < 64) {
        int rank = 0;
#pragma unroll
        for (int g = 0; g < 8; ++g) rank += part[tid + 64 * g];
        int ee = c * 64 + tid;
        float v = s2p[b * N_ + ee] + s2p[(size_t)B_ * N_ + b * N_ + ee];
        ssort[b * N_ + rank] = v;
        sord[b * N_ + rank]  = ee;
        e2p[b * N_ + rank] = expf(v);
        e2n[b * N_ + rank] = expf(ALPHA * v);
    }
}

// ---------------- KX: chunk-local full prefixes (blocks 0..255) ∪ scalar scan+cutoffs (256..263) ----------------
__global__ __launch_bounds__(512) void kx_scan(const float* __restrict__ Wh,
                                               const int* __restrict__ sord,
                                               const float* __restrict__ e2p,
                                               const float* __restrict__ e2n,
                                               const float* __restrict__ ssort,
                                               const float* __restrict__ s1p,
                                               float2* __restrict__ SPN,
                                               float2* __restrict__ DPN,
                                               int* __restrict__ kcut) {
    __shared__ float2 qt[4][FO];     // chunk part
    __shared__ float sv[N_];         // scan part
    __shared__ float2 wsum[8];
    const int tid = threadIdx.x;
    const int bid = blockIdx.x;

    if (bid < 256) {
        // one 64-chunk; q = tid>>7 owns 16 positions; full chunk-local prefixes out
        const int b = bid >> 5, ch = bid & 31;
        const int f = tid & 127, q = tid >> 7;
        const size_t base = (size_t)b * N_;
        const int ks = ch * CHUNK + q * 16;

        int ords[16]; float wp[16], wn[16], xv[16];
#pragma unroll
        for (int j = 0; j < 16; ++j) ords[j] = sord[base + ks + j];
#pragma unroll
        for (int j = 0; j < 16; ++j) { wp[j] = e2p[base + ks + j]; wn[j] = e2n[base + ks + j]; }
#pragma unroll
        for (int j = 0; j < 16; ++j) xv[j] = Wh[(base + ords[j]) * FO + f];

        float2 s[16];
        float ap = 0.f, an = 0.f;
#pragma unroll
        for (int j = 0; j < 16; ++j) {
            ap += wp[j] * xv[j];
            an += wn[j] * xv[j];
            s[j] = make_float2(ap, an);
        }
        qt[q][f] = make_float2(ap, an);
        __syncthreads();

        float op = 0.f, on = 0.f;
#pragma unroll
        for (int q2 = 0; q2 < 3; ++q2)
            if (q2 < q) { op += qt[q2][f].x; on += qt[q2][f].y; }

#pragma unroll
        for (int j = 0; j < 16; ++j)
            SPN[(base + ks + j) * FO + f] = make_float2(s[j].x + op, s[j].y + on);
    } else {
        // per-batch scalar scan + cutoffs
        const int b = bid - 256;
        const size_t base = (size_t)b * N_;

        float v[4], pv[4], nv[4], lp[4], ln[4];
        *(float4*)&v[0]  = *(const float4*)&ssort[base + tid * 4];
        *(float4*)&pv[0] = *(const float4*)&e2p[base + tid * 4];
        *(float4*)&nv[0] = *(const float4*)&e2n[base + tid * 4];
        float ap = 0.f, an = 0.f;
#pragma unroll
        for (int j = 0; j < 4; ++j) {
            sv[tid * 4 + j] = v[j];
            ap += pv[j]; lp[j] = ap;
            an += nv[j]; ln[j] = an;
        }

        float ip = ap, in2 = an;
        const int lane = tid & 63;
#pragma unroll
        for (int off = 1; off < 64; off <<= 1) {
            float tpv = __shfl_up(ip, off);
            float tnv = __shfl_up(in2, off);
            if (lane >= off) { ip += tpv; in2 += tnv; }
        }
        if (lane == 63) wsum[tid >> 6] = make_float2(ip, in2);
        __syncthreads();

        float basP = ip - ap, basN = in2 - an;
        const int w = tid >> 6;
#pragma unroll
        for (int w2 = 0; w2 < 7; ++w2)
            if (w2 < w) { basP += wsum[w2].x; basN += wsum[w2].y; }
#pragma unroll
        for (int j = 0; j < 4; ++j)
            DPN[base + tid * 4 + j] = make_float2(lp[j] + basP, ln[j] + basN);

        float tgt[4];
        int lo[4], hi[4];
#pragma unroll
        for (int r = 0; r < 4; ++r) {
            int row = tid + 512 * r;
            tgt[r] = -(s1p[base + row] + s1p[(size_t)B_ * N_ + base + row]);
            lo[r] = 0; hi[r] = N_;
        }
#pragma unroll
        for (int step = 0; step < 11; ++step) {
#pragma unroll
            for (int r = 0; r < 4; ++r) {
                int mid = (lo[r] + hi[r]) >> 1;
                bool live = lo[r] < hi[r];
                float pv2 = sv[mid & (N_ - 1)];
                bool cc = live && (pv2 >= tgt[r]);
                lo[r] = cc ? mid + 1 : lo[r];
                hi[r] = (live && !cc) ? mid : hi[r];
            }
        }
#pragma unroll
        for (int r = 0; r < 4; ++r) kcut[base + tid + 512 * r] = lo[r];
    }
}

// ---------------- K4: per-32-row block; ct scan + 1 prefix load per row; no gather ----------------
// grid = 512 blocks, 512 threads (4 rows x 128 f per iteration, 8 iters)
__global__ __launch_bounds__(512) void k4_final(const float* __restrict__ s1p,
                                                const int* __restrict__ kcut,
                                                const float2* __restrict__ DPN,
                                                const float2* __restrict__ SPN,
                                                float* __restrict__ out) {
    __shared__ float2 ct[NCHUNK][FO];        // 32 KB -> becomes exclusive prefix
    __shared__ float2 qTot[4][FO];           // 4 KB
    __shared__ float sntN_lds[FO];
    __shared__ float2 s1e_lds[32];           // (exp(s1), exp(a*s1)) per row
    __shared__ float2 dpn_lds[32];           // DPN[km1] per row
    __shared__ int    k_lds[32];

    const int bid = blockIdx.x;
    const int b   = bid >> 6;                // 64 blocks per batch
    const int r0  = (bid & 63) * 32;         // first row of this block
    const int tid = threadIdx.x;
    const int f = tid & 127, rr = tid >> 7;  // rr = 0..3
    const size_t base = (size_t)b * N_;

    // 1) stage 32 chunk totals (last position of each chunk)
    for (int idx = tid; idx < NCHUNK * FO; idx += 512) {
        int c = idx >> 7, ff = idx & 127;
        ct[c][ff] = SPN[(base + c * CHUNK + CHUNK - 1) * FO + ff];
    }
    // stage per-row scalars
    if (tid < 32) {
        int row = r0 + tid;
        int k = kcut[base + row];
        k_lds[tid] = k;
        float s1v = s1p[base + row] + s1p[(size_t)B_ * N_ + base + row];
        s1e_lds[tid] = make_float2(expf(s1v), expf(ALPHA * s1v));
        dpn_lds[tid] = (k > 0) ? DPN[base + k - 1] : make_float2(0.f, 0.f);
    }
    __syncthreads();

    // 2) exclusive scan over chunks: 4 quarters of 8 + fixup
    float rp = 0.f, rn = 0.f;
    for (int c = rr * 8; c < rr * 8 + 8; ++c) {
        float2 t = ct[c][f];
        ct[c][f] = make_float2(rp, rn);
        rp += t.x; rn += t.y;
    }
    qTot[rr][f] = make_float2(rp, rn);
    __syncthreads();
    float addP = 0.f, addN = 0.f;
#pragma unroll
    for (int q2 = 0; q2 < 3; ++q2)
        if (q2 < rr) { addP += qTot[q2][f].x; addN += qTot[q2][f].y; }
    if (rr > 0) {
        for (int c = rr * 8; c < rr * 8 + 8; ++c) {
            float2 t = ct[c][f];
            ct[c][f] = make_float2(t.x + addP, t.y + addN);
        }
    }
    if (tid < FO)
        sntN_lds[tid] = qTot[0][tid].y + qTot[1][tid].y + qTot[2][tid].y + qTot[3][tid].y;
    __syncthreads();

    const float dnt = DPN[base + N_ - 1].y;
    const float sntN = sntN_lds[f];

    // 3) 8 iterations x 4 rows; one coalesced prefix load per row
#pragma unroll 2
    for (int it = 0; it < 8; ++it) {
        const int lr   = it * 4 + rr;        // local row 0..31
        const int row  = r0 + lr;
        const float2 e1 = s1e_lds[lr];
        const float2 d  = dpn_lds[lr];
        const int k = k_lds[lr];

        float sp = 0.f, sn = 0.f;
        if (k > 0) {
            const int km1 = k - 1;
            const int c32 = km1 >> 6;          // CHUNK=64
            float2 o  = ct[c32][f];
            float2 sl = SPN[(base + km1) * FO + f];
            sp = o.x + sl.x;
            sn = o.y + sl.y;
        }
        const float den = e1.x * d.x + e1.y * (dnt - d.y);
        const float num = e1.x * sp + e1.y * (sntN - sn);
        const float o = num / den;
        out[((size_t)b * N_ + row) * FO + f] = (o > 0.f) ? o : (expf(o) - 1.f);
    }
}

// ---------------- launch ----------------
extern "C" void kernel_launch(void* const* d_in, const int* in_sizes, int n_in,
                              void* d_out, int out_size, void* d_ws, size_t ws_size,
                              hipStream_t stream) {
    const float* h = (const float*)d_in[0];
    const float* W = (const float*)d_in[1];
    const float* a = (const float*)d_in[2];
    float* out = (float*)d_out;
    float* ws = (float*)d_ws;

    float*  Wh    = ws + OFF_WH;
    float*  s1p   = ws + OFF_S1P;
    float*  s2p   = ws + OFF_S2P;
    float*  ssort = ws + OFF_SSORT;
    int*    sord  = (int*)(ws + OFF_SORD);
    float*  e2p   = ws + OFF_E2P;
    float*  e2n   = ws + OFF_E2N;
    float2* DPN   = (float2*)(ws + OFF_DPN);
    int*    kcut  = (int*)(ws + OFF_KCUT);
    float2* SPN   = (float2*)(ws + OFF_SPN);

    k1_gemm<<<dim3(512), dim3(256), 0, stream>>>(h, W, a, Wh, s1p, s2p);
    k2a_rank<<<dim3(B_ * 32), dim3(512), 0, stream>>>(s2p, ssort, sord, e2p, e2n);
    kx_scan<<<dim3(264), dim3(512), 0, stream>>>(Wh, sord, e2p, e2n, ssort, s1p,
                                                 SPN, DPN, kcut);
    k4_final<<<dim3(512), dim3(512), 0, stream>>>(s1p, kcut, DPN, SPN, out);
}

// Round 11
// 45.433 us; speedup vs baseline: 4.9173x; 1.1676x over previous
//
#include <hip/hip_runtime.h>
#include <math.h>
#include <stdint.h>

#define B_    8
#define N_    2048
#define FIN   256
#define FO    128
#define ALPHA 0.2f
#define NCHUNK 32
#define CHUNK  64    // N_/NCHUNK

typedef __attribute__((ext_vector_type(8))) __bf16 bf16x8;
typedef __attribute__((ext_vector_type(8))) short short8_t;
typedef __attribute__((ext_vector_type(4))) short short4_t;
typedef __attribute__((ext_vector_type(4))) float f32x4;

// ---------------- workspace layout (float elements) ----------------
static const size_t OFF_WH    = 0;                                    // B*N*FO
static const size_t OFF_S1P   = OFF_WH    + (size_t)B_*N_*FO;         // 4*B*N (four n-group partials)
static const size_t OFF_S2P   = OFF_S1P   + (size_t)4*B_*N_;          // 4*B*N
static const size_t OFF_SSORT = OFF_S2P   + (size_t)4*B_*N_;
static const size_t OFF_SORD  = OFF_SSORT + (size_t)B_*N_;
static const size_t OFF_E2P   = OFF_SORD  + (size_t)B_*N_;
static const size_t OFF_E2N   = OFF_E2P   + (size_t)B_*N_;
static const size_t OFF_DPN   = OFF_E2N   + (size_t)B_*N_;            // float2 * B*N
static const size_t OFF_KCUT  = OFF_DPN   + (size_t)2*B_*N_;
static const size_t OFF_SPN   = OFF_KCUT  + (size_t)B_*N_;            // float2 * B*N*FO (chunk-local prefixes)

__device__ __forceinline__ unsigned short bf16_rne(float x) {
    unsigned u = __float_as_uint(x);
    unsigned r = (u + 0x7FFFu + ((u >> 16) & 1u)) >> 16;
    return (unsigned short)r;
}

// ---------------- K1: Wh = h @ W via split-bf16 MFMA (+ 4-group partial s1,s2) ----------------
// 256 blocks (BM=64, BN=128), 512 threads = 8 waves: wave = (mh 0..1) x (ng 0..3).
// Wave computes 2x2 16x16 tiles: mt = mh*2+i, nt = ng*2+j. 3 MFMA per tile per K-step.
__global__ __launch_bounds__(512) void k1_gemm(const float* __restrict__ h,
                                               const float* __restrict__ W,
                                               const float* __restrict__ a,
                                               float* __restrict__ Wh,
                                               float* __restrict__ s1p,
                                               float* __restrict__ s2p) {
    __shared__ short hS_hi[64][40], hS_lo[64][40];     // [row][k], pad 40 (80B rows, 16B-aligned)
    __shared__ short wS_hi[128][40], wS_lo[128][40];   // [col][k]

    const int tid  = threadIdx.x;
    const int lane = tid & 63, wv = tid >> 6;
    const int mh = wv & 1, ng = wv >> 1;
    const int l15 = lane & 15, l4 = lane >> 4;
    const int row0 = blockIdx.x * 64;

    // staging maps
    const int h_r = tid >> 3, h_kq = (tid & 7) * 4;    // h: one float4 per thread
    const int w_c = tid & 127, w_kb = (tid >> 7) * 8;  // W: col-owner, 8 k-scalars

    f32x4 acc[2][2];
#pragma unroll
    for (int i = 0; i < 2; ++i)
#pragma unroll
        for (int j = 0; j < 2; ++j) acc[i][j] = (f32x4){0.f, 0.f, 0.f, 0.f};

    // prefetch k0 = 0
    float4 hv = *(const float4*)&h[(size_t)(row0 + h_r) * FIN + h_kq];
    float wf[8];
#pragma unroll
    for (int s = 0; s < 8; ++s) wf[s] = W[(size_t)(w_kb + s) * FO + w_c];

    for (int k0 = 0; k0 < FIN; k0 += 32) {
        // ---- convert + write LDS ----
        {
            float hf[4] = {hv.x, hv.y, hv.z, hv.w};
            short4_t hhi, hlo;
#pragma unroll
            for (int s = 0; s < 4; ++s) {
                unsigned short hb = bf16_rne(hf[s]);
                float hbf = __uint_as_float((unsigned)hb << 16);
                hhi[s] = (short)hb;
                hlo[s] = (short)bf16_rne(hf[s] - hbf);
            }
            *(short4_t*)&hS_hi[h_r][h_kq] = hhi;
            *(short4_t*)&hS_lo[h_r][h_kq] = hlo;

            short8_t whi, wlo;
#pragma unroll
            for (int s = 0; s < 8; ++s) {
                unsigned short wb = bf16_rne(wf[s]);
                float wbf = __uint_as_float((unsigned)wb << 16);
                whi[s] = (short)wb;
                wlo[s] = (short)bf16_rne(wf[s] - wbf);
            }
            *(short8_t*)&wS_hi[w_c][w_kb] = whi;
            *(short8_t*)&wS_lo[w_c][w_kb] = wlo;
        }
        __syncthreads();

        // ---- prefetch next tile ----
        if (k0 + 32 < FIN) {
            hv = *(const float4*)&h[(size_t)(row0 + h_r) * FIN + k0 + 32 + h_kq];
#pragma unroll
            for (int s = 0; s < 8; ++s)
                wf[s] = W[(size_t)(k0 + 32 + w_kb + s) * FO + w_c];
        }

        // ---- fragment loads + MFMA ----
        bf16x8 a_hi[2], a_lo[2], b_hi[2], b_lo[2];
#pragma unroll
        for (int i = 0; i < 2; ++i) {
            int r = (mh * 2 + i) * 16 + l15;
            a_hi[i] = __builtin_bit_cast(bf16x8, *(short8_t*)&hS_hi[r][l4 * 8]);
            a_lo[i] = __builtin_bit_cast(bf16x8, *(short8_t*)&hS_lo[r][l4 * 8]);
        }
#pragma unroll
        for (int j = 0; j < 2; ++j) {
            int c = (ng * 2 + j) * 16 + l15;
            b_hi[j] = __builtin_bit_cast(bf16x8, *(short8_t*)&wS_hi[c][l4 * 8]);
            b_lo[j] = __builtin_bit_cast(bf16x8, *(short8_t*)&wS_lo[c][l4 * 8]);
        }
#pragma unroll
        for (int i = 0; i < 2; ++i)
#pragma unroll
            for (int j = 0; j < 2; ++j) {
                acc[i][j] = __builtin_amdgcn_mfma_f32_16x16x32_bf16(a_hi[i], b_hi[j], acc[i][j], 0, 0, 0);
                acc[i][j] = __builtin_amdgcn_mfma_f32_16x16x32_bf16(a_hi[i], b_lo[j], acc[i][j], 0, 0, 0);
                acc[i][j] = __builtin_amdgcn_mfma_f32_16x16x32_bf16(a_lo[i], b_hi[j], acc[i][j], 0, 0, 0);
            }
        __syncthreads();
    }

    // ---- write Wh: row=(mh*2+i)*16 + l4*4 + reg, col=(ng*2+j)*16 + l15 ----
#pragma unroll
    for (int i = 0; i < 2; ++i)
#pragma unroll
        for (int j = 0; j < 2; ++j) {
            int colg = (ng * 2 + j) * 16 + l15;
#pragma unroll
            for (int reg = 0; reg < 4; ++reg) {
                int rowg = row0 + (mh * 2 + i) * 16 + l4 * 4 + reg;
                Wh[(size_t)rowg * FO + colg] = acc[i][j][reg];
            }
        }

    // ---- s1/s2 partials: shuffle-reduce over 16 cols, write per-ng partial ----
    float a1v[2], a2v[2];
#pragma unroll
    for (int j = 0; j < 2; ++j) {
        int c = (ng * 2 + j) * 16 + l15;
        a1v[j] = a[c];
        a2v[j] = a[FO + c];
    }
#pragma unroll
    for (int i = 0; i < 2; ++i) {
        float p1[4], p2[4];
#pragma unroll
        for (int reg = 0; reg < 4; ++reg) {
            p1[reg] = acc[i][0][reg] * a1v[0] + acc[i][1][reg] * a1v[1];
            p2[reg] = acc[i][0][reg] * a2v[0] + acc[i][1][reg] * a2v[1];
        }
#pragma unroll
        for (int m = 1; m < 16; m <<= 1) {
#pragma unroll
            for (int reg = 0; reg < 4; ++reg) {
                p1[reg] += __shfl_xor(p1[reg], m);
                p2[reg] += __shfl_xor(p2[reg], m);
            }
        }
        if (l15 == 0) {
#pragma unroll
            for (int reg = 0; reg < 4; ++reg) {
                int rowg = row0 + (mh * 2 + i) * 16 + l4 * 4 + reg;
                s1p[(size_t)ng * (B_ * N_) + rowg] = p1[reg];
                s2p[(size_t)ng * (B_ * N_) + rowg] = p2[reg];
            }
        }
    }
}

// ---------------- K2a: brute-force rank + scatter + exps ----------------
__global__ __launch_bounds__(512) void k2a_rank(const float* __restrict__ s2p,
                                                float* __restrict__ ssort,
                                                int* __restrict__ sord,
                                                float* __restrict__ e2p,
                                                float* __restrict__ e2n) {
    __shared__ uint64_t keys[N_];   // 16 KB
    __shared__ int part[512];
    const int b = blockIdx.x >> 5, c = blockIdx.x & 31;
    const int tid = threadIdx.x;
    const size_t SZ = (size_t)B_ * N_;

    for (int t = tid; t < N_; t += 512) {
        size_t ix = (size_t)b * N_ + t;
        float s2v = s2p[ix] + s2p[SZ + ix] + s2p[2 * SZ + ix] + s2p[3 * SZ + ix];
        unsigned u = __float_as_uint(s2v);
        u = (u & 0x80000000u) ? ~u : (u | 0x80000000u);   // order-preserving map
        keys[t] = ((uint64_t)u << 16) | (unsigned)t;      // unique -> no ties
    }
    __syncthreads();

    const int le = tid & 63;
    const int e  = c * 64 + le;
    const int q  = tid >> 6;         // 0..7
    const uint64_t myk = keys[e];
    const uint64_t* kp = keys + q * 256;
    int cnt = 0;
#pragma unroll 8
    for (int kk = 0; kk < 256; ++kk) cnt += (int)(kp[kk] > myk);
    part[tid] = cnt;
    __syncthreads();

    if (tid < 64) {
        int rank = 0;
#pragma unroll
        for (int g = 0; g < 8; ++g) rank += part[tid + 64 * g];
        int ee = c * 64 + tid;
        size_t ix = (size_t)b * N_ + ee;
        float v = s2p[ix] + s2p[SZ + ix] + s2p[2 * SZ + ix] + s2p[3 * SZ + ix];
        ssort[b * N_ + rank] = v;
        sord[b * N_ + rank]  = ee;
        e2p[b * N_ + rank] = expf(v);
        e2n[b * N_ + rank] = expf(ALPHA * v);
    }
}

// ---------------- KX: chunk-local full prefixes (blocks 0..255) ∪ scalar scan+cutoffs (256..263) ----------------
__global__ __launch_bounds__(512) void kx_scan(const float* __restrict__ Wh,
                                               const int* __restrict__ sord,
                                               const float* __restrict__ e2p,
                                               const float* __restrict__ e2n,
                                               const float* __restrict__ ssort,
                                               const float* __restrict__ s1p,
                                               float2* __restrict__ SPN,
                                               float2* __restrict__ DPN,
                                               int* __restrict__ kcut) {
    __shared__ float2 qt[4][FO];     // chunk part
    __shared__ float sv[N_];         // scan part
    __shared__ float2 wsum[8];
    const int tid = threadIdx.x;
    const int bid = blockIdx.x;
    const size_t SZ = (size_t)B_ * N_;

    if (bid < 256) {
        // one 64-chunk; q = tid>>7 owns 16 positions; full chunk-local prefixes out
        const int b = bid >> 5, ch = bid & 31;
        const int f = tid & 127, q = tid >> 7;
        const size_t base = (size_t)b * N_;
        const int ks = ch * CHUNK + q * 16;

        int ords[16]; float wp[16], wn[16], xv[16];
#pragma unroll
        for (int j = 0; j < 16; ++j) ords[j] = sord[base + ks + j];
#pragma unroll
        for (int j = 0; j < 16; ++j) { wp[j] = e2p[base + ks + j]; wn[j] = e2n[base + ks + j]; }
#pragma unroll
        for (int j = 0; j < 16; ++j) xv[j] = Wh[(base + ords[j]) * FO + f];

        float2 s[16];
        float ap = 0.f, an = 0.f;
#pragma unroll
        for (int j = 0; j < 16; ++j) {
            ap += wp[j] * xv[j];
            an += wn[j] * xv[j];
            s[j] = make_float2(ap, an);
        }
        qt[q][f] = make_float2(ap, an);
        __syncthreads();

        float op = 0.f, on = 0.f;
#pragma unroll
        for (int q2 = 0; q2 < 3; ++q2)
            if (q2 < q) { op += qt[q2][f].x; on += qt[q2][f].y; }

#pragma unroll
        for (int j = 0; j < 16; ++j)
            SPN[(base + ks + j) * FO + f] = make_float2(s[j].x + op, s[j].y + on);
    } else {
        // per-batch scalar scan + cutoffs
        const int b = bid - 256;
        const size_t base = (size_t)b * N_;

        float v[4], pv[4], nv[4], lp[4], ln[4];
        *(float4*)&v[0]  = *(const float4*)&ssort[base + tid * 4];
        *(float4*)&pv[0] = *(const float4*)&e2p[base + tid * 4];
        *(float4*)&nv[0] = *(const float4*)&e2n[base + tid * 4];
        float ap = 0.f, an = 0.f;
#pragma unroll
        for (int j = 0; j < 4; ++j) {
            sv[tid * 4 + j] = v[j];
            ap += pv[j]; lp[j] = ap;
            an += nv[j]; ln[j] = an;
        }

        float ip = ap, in2 = an;
        const int lane = tid & 63;
#pragma unroll
        for (int off = 1; off < 64; off <<= 1) {
            float tpv = __shfl_up(ip, off);
            float tnv = __shfl_up(in2, off);
            if (lane >= off) { ip += tpv; in2 += tnv; }
        }
        if (lane == 63) wsum[tid >> 6] = make_float2(ip, in2);
        __syncthreads();

        float basP = ip - ap, basN = in2 - an;
        const int w = tid >> 6;
#pragma unroll
        for (int w2 = 0; w2 < 7; ++w2)
            if (w2 < w) { basP += wsum[w2].x; basN += wsum[w2].y; }
#pragma unroll
        for (int j = 0; j < 4; ++j)
            DPN[base + tid * 4 + j] = make_float2(lp[j] + basP, ln[j] + basN);

        float tgt[4];
        int lo[4], hi[4];
#pragma unroll
        for (int r = 0; r < 4; ++r) {
            size_t row = base + tid + 512 * r;
            tgt[r] = -(s1p[row] + s1p[SZ + row] + s1p[2 * SZ + row] + s1p[3 * SZ + row]);
            lo[r] = 0; hi[r] = N_;
        }
#pragma unroll
        for (int step = 0; step < 11; ++step) {
#pragma unroll
            for (int r = 0; r < 4; ++r) {
                int mid = (lo[r] + hi[r]) >> 1;
                bool live = lo[r] < hi[r];
                float pv2 = sv[mid & (N_ - 1)];
                bool cc = live && (pv2 >= tgt[r]);
                lo[r] = cc ? mid + 1 : lo[r];
                hi[r] = (live && !cc) ? mid : hi[r];
            }
        }
#pragma unroll
        for (int r = 0; r < 4; ++r) kcut[base + tid + 512 * r] = lo[r];
    }
}

// ---------------- K4: per-32-row block; ct scan + 1 prefix load per row; no gather ----------------
// grid = 512 blocks, 512 threads (4 rows x 128 f per iteration, 8 iters)
__global__ __launch_bounds__(512) void k4_final(const float* __restrict__ s1p,
                                                const int* __restrict__ kcut,
                                                const float2* __restrict__ DPN,
                                                const float2* __restrict__ SPN,
                                                float* __restrict__ out) {
    __shared__ float2 ct[NCHUNK][FO];        // 32 KB -> becomes exclusive prefix
    __shared__ float2 qTot[4][FO];           // 4 KB
    __shared__ float sntN_lds[FO];
    __shared__ float2 s1e_lds[32];           // (exp(s1), exp(a*s1)) per row
    __shared__ float2 dpn_lds[32];           // DPN[km1] per row
    __shared__ int    k_lds[32];

    const int bid = blockIdx.x;
    const int b   = bid >> 6;                // 64 blocks per batch
    const int r0  = (bid & 63) * 32;         // first row of this block
    const int tid = threadIdx.x;
    const int f = tid & 127, rr = tid >> 7;  // rr = 0..3
    const size_t base = (size_t)b * N_;
    const size_t SZ = (size_t)B_ * N_;

    // 1) stage 32 chunk totals (last position of each chunk)
    for (int idx = tid; idx < NCHUNK * FO; idx += 512) {
        int c = idx >> 7, ff = idx & 127;
        ct[c][ff] = SPN[(base + c * CHUNK + CHUNK - 1) * FO + ff];
    }
    // stage per-row scalars
    if (tid < 32) {
        int row = r0 + tid;
        int k = kcut[base + row];
        k_lds[tid] = k;
        size_t rix = base + row;
        float s1v = s1p[rix] + s1p[SZ + rix] + s1p[2 * SZ + rix] + s1p[3 * SZ + rix];
        s1e_lds[tid] = make_float2(expf(s1v), expf(ALPHA * s1v));
        dpn_lds[tid] = (k > 0) ? DPN[base + k - 1] : make_float2(0.f, 0.f);
    }
    __syncthreads();

    // 2) exclusive scan over chunks: 4 quarters of 8 + fixup
    float rp = 0.f, rn = 0.f;
    for (int c = rr * 8; c < rr * 8 + 8; ++c) {
        float2 t = ct[c][f];
        ct[c][f] = make_float2(rp, rn);
        rp += t.x; rn += t.y;
    }
    qTot[rr][f] = make_float2(rp, rn);
    __syncthreads();
    float addP = 0.f, addN = 0.f;
#pragma unroll
    for (int q2 = 0; q2 < 3; ++q2)
        if (q2 < rr) { addP += qTot[q2][f].x; addN += qTot[q2][f].y; }
    if (rr > 0) {
        for (int c = rr * 8; c < rr * 8 + 8; ++c) {
            float2 t = ct[c][f];
            ct[c][f] = make_float2(t.x + addP, t.y + addN);
        }
    }
    if (tid < FO)
        sntN_lds[tid] = qTot[0][tid].y + qTot[1][tid].y + qTot[2][tid].y + qTot[3][tid].y;
    __syncthreads();

    const float dnt = DPN[base + N_ - 1].y;
    const float sntN = sntN_lds[f];

    // 3) 8 iterations x 4 rows; one coalesced prefix load per row
#pragma unroll 2
    for (int it = 0; it < 8; ++it) {
        const int lr   = it * 4 + rr;        // local row 0..31
        const int row  = r0 + lr;
        const float2 e1 = s1e_lds[lr];
        const float2 d  = dpn_lds[lr];
        const int k = k_lds[lr];

        float sp = 0.f, sn = 0.f;
        if (k > 0) {
            const int km1 = k - 1;
            const int c32 = km1 >> 6;          // CHUNK=64
            float2 o  = ct[c32][f];
            float2 sl = SPN[(base + km1) * FO + f];
            sp = o.x + sl.x;
            sn = o.y + sl.y;
        }
        const float den = e1.x * d.x + e1.y * (dnt - d.y);
        const float num = e1.x * sp + e1.y * (sntN - sn);
        const float o = num / den;
        out[((size_t)b * N_ + row) * FO + f] = (o > 0.f) ? o : (expf(o) - 1.f);
    }
}

// ---------------- launch ----------------
extern "C" void kernel_launch(void* const* d_in, const int* in_sizes, int n_in,
                              void* d_out, int out_size, void* d_ws, size_t ws_size,
                              hipStream_t stream) {
    const float* h = (const float*)d_in[0];
    const float* W = (const float*)d_in[1];
    const float* a = (const float*)d_in[2];
    float* out = (float*)d_out;
    float* ws = (float*)d_ws;

    float*  Wh    = ws + OFF_WH;
    float*  s1p   = ws + OFF_S1P;
    float*  s2p   = ws + OFF_S2P;
    float*  ssort = ws + OFF_SSORT;
    int*    sord  = (int*)(ws + OFF_SORD);
    float*  e2p   = ws + OFF_E2P;
    float*  e2n   = ws + OFF_E2N;
    float2* DPN   = (float2*)(ws + OFF_DPN);
    int*    kcut  = (int*)(ws + OFF_KCUT);
    float2* SPN   = (float2*)(ws + OFF_SPN);

    k1_gemm<<<dim3(B_ * N_ / 64), dim3(512), 0, stream>>>(h, W, a, Wh, s1p, s2p);
    k2a_rank<<<dim3(B_ * 32), dim3(512), 0, stream>>>(s2p, ssort, sord, e2p, e2n);
    kx_scan<<<dim3(264), dim3(512), 0, stream>>>(Wh, sord, e2p, e2n, ssort, s1p,
                                                 SPN, DPN, kcut);
    k4_final<<<dim3(512), dim3(512), 0, stream>>>(s1p, kcut, DPN, SPN, out);
}